// Round 2
// baseline (2922.032 us; speedup 1.0000x reference)
//
#include <hip/hip_runtime.h>
#include <hip/hip_bf16.h>
#include <cstdint>

// Problem constants (Multinomial VAE)
#define BB 4096
#define DD 1024
#define HH 1024
#define LL 4
#define NTRIAL 24
#define VV 2925
#define TAU_INV 100.0f
#define LOG_TINY -87.336544750402f  // logf(1.17549435e-38f)

// ---------------------------------------------------------------------------
// fp32 GEMM: C = act(A @ W + bias), A (M,K) row-major, W (K,N) row-major.
// 128x128 tile, BK=16, 256 threads, 8x8 per thread, double-buffered LDS.
// ---------------------------------------------------------------------------
#define BM 128
#define BN 128
#define BK 16
#define PAD 4

template <bool RELU>
__global__ __launch_bounds__(256, 2) void gemm_rowrow(
    const float* __restrict__ A, const float* __restrict__ W,
    const float* __restrict__ bias, float* __restrict__ C,
    int M, int Nn, int K) {
  __shared__ float As[2][BK][BM + PAD];
  __shared__ float Bs[2][BK][BN + PAD];

  const int tid = threadIdx.x;
  const int m0 = blockIdx.y * BM;
  const int n0 = blockIdx.x * BN;
  const int tr = tid >> 4;    // 0..15 -> row group (8 rows)
  const int tc = tid & 15;    // 0..15 -> col group (4 + 4 cols, split by 64)

  // staging thread mapping
  const int arow = tid >> 2;          // 0..63
  const int acol = (tid & 3) << 2;    // 0,4,8,12
  const int brow = tid >> 5;          // 0..7
  const int bcol = (tid & 31) << 2;   // 0..124

  const float* Ap0 = A + (size_t)(m0 + arow) * K + acol;
  const float* Ap1 = Ap0 + (size_t)64 * K;
  const float* Wp0 = W + (size_t)brow * Nn + n0 + bcol;
  const float* Wp1 = Wp0 + (size_t)8 * Nn;

  float4 ra0 = *(const float4*)Ap0;
  float4 ra1 = *(const float4*)Ap1;
  float4 rb0 = *(const float4*)Wp0;
  float4 rb1 = *(const float4*)Wp1;

  float acc[8][8];
#pragma unroll
  for (int i = 0; i < 8; ++i)
#pragma unroll
    for (int j = 0; j < 8; ++j) acc[i][j] = 0.0f;

  // write tile 0
  {
    As[0][acol + 0][arow] = ra0.x;
    As[0][acol + 1][arow] = ra0.y;
    As[0][acol + 2][arow] = ra0.z;
    As[0][acol + 3][arow] = ra0.w;
    As[0][acol + 0][arow + 64] = ra1.x;
    As[0][acol + 1][arow + 64] = ra1.y;
    As[0][acol + 2][arow + 64] = ra1.z;
    As[0][acol + 3][arow + 64] = ra1.w;
    *(float4*)&Bs[0][brow][bcol] = rb0;
    *(float4*)&Bs[0][brow + 8][bcol] = rb1;
  }
  __syncthreads();

  const int nk = K / BK;
  int cur = 0;
#pragma unroll 1
  for (int kt = 0; kt < nk; ++kt) {
    const bool more = (kt + 1 < nk);
    if (more) {
      Ap0 += BK;
      Ap1 += BK;
      Wp0 += (size_t)BK * Nn;
      Wp1 += (size_t)BK * Nn;
      ra0 = *(const float4*)Ap0;
      ra1 = *(const float4*)Ap1;
      rb0 = *(const float4*)Wp0;
      rb1 = *(const float4*)Wp1;
    }
#pragma unroll
    for (int kk = 0; kk < BK; ++kk) {
      const float4 a0 = *(const float4*)&As[cur][kk][tr * 8];
      const float4 a1 = *(const float4*)&As[cur][kk][tr * 8 + 4];
      const float4 b0 = *(const float4*)&Bs[cur][kk][tc * 4];
      const float4 b1 = *(const float4*)&Bs[cur][kk][tc * 4 + 64];
      const float av[8] = {a0.x, a0.y, a0.z, a0.w, a1.x, a1.y, a1.z, a1.w};
      const float bv[8] = {b0.x, b0.y, b0.z, b0.w, b1.x, b1.y, b1.z, b1.w};
#pragma unroll
      for (int i = 0; i < 8; ++i)
#pragma unroll
        for (int j = 0; j < 8; ++j) acc[i][j] = fmaf(av[i], bv[j], acc[i][j]);
    }
    if (more) {
      const int nxt = cur ^ 1;
      As[nxt][acol + 0][arow] = ra0.x;
      As[nxt][acol + 1][arow] = ra0.y;
      As[nxt][acol + 2][arow] = ra0.z;
      As[nxt][acol + 3][arow] = ra0.w;
      As[nxt][acol + 0][arow + 64] = ra1.x;
      As[nxt][acol + 1][arow + 64] = ra1.y;
      As[nxt][acol + 2][arow + 64] = ra1.z;
      As[nxt][acol + 3][arow + 64] = ra1.w;
      *(float4*)&Bs[nxt][brow][bcol] = rb0;
      *(float4*)&Bs[nxt][brow + 8][bcol] = rb1;
      __syncthreads();
      cur = nxt;
    }
  }

  // epilogue: bias + optional relu
  const float4 bb0 = *(const float4*)&bias[n0 + tc * 4];
  const float4 bb1 = *(const float4*)&bias[n0 + 64 + tc * 4];
#pragma unroll
  for (int i = 0; i < 8; ++i) {
    const int row = m0 + tr * 8 + i;
    float* Cp = C + (size_t)row * Nn + n0;
    float4 o0, o1;
    o0.x = acc[i][0] + bb0.x;
    o0.y = acc[i][1] + bb0.y;
    o0.z = acc[i][2] + bb0.z;
    o0.w = acc[i][3] + bb0.w;
    o1.x = acc[i][4] + bb1.x;
    o1.y = acc[i][5] + bb1.y;
    o1.z = acc[i][6] + bb1.z;
    o1.w = acc[i][7] + bb1.w;
    if (RELU) {
      o0.x = fmaxf(o0.x, 0.f); o0.y = fmaxf(o0.y, 0.f);
      o0.z = fmaxf(o0.z, 0.f); o0.w = fmaxf(o0.w, 0.f);
      o1.x = fmaxf(o1.x, 0.f); o1.y = fmaxf(o1.y, 0.f);
      o1.z = fmaxf(o1.z, 0.f); o1.w = fmaxf(o1.w, 0.f);
    }
    *(float4*)&Cp[tc * 4] = o0;
    *(float4*)&Cp[64 + tc * 4] = o1;
  }
}

// ---------------------------------------------------------------------------
// Encoder head: logits = h2 @ enc_w3 + b3 (K=1024, 4 outputs), softmax -> logp
// one wave per row, 4 rows per block.
// ---------------------------------------------------------------------------
__global__ __launch_bounds__(256) void enc_head(
    const float* __restrict__ h2, const float* __restrict__ w3,
    const float* __restrict__ b3, float* __restrict__ logp) {
  const int wave = threadIdx.x >> 6;
  const int lane = threadIdx.x & 63;
  const int row = blockIdx.x * 4 + wave;
  const float* h = h2 + (size_t)row * HH;
  float a0 = 0.f, a1 = 0.f, a2 = 0.f, a3 = 0.f;
#pragma unroll
  for (int k = lane; k < HH; k += 64) {
    const float hv = h[k];
    const float4 w = *(const float4*)&w3[k * 4];
    a0 = fmaf(hv, w.x, a0);
    a1 = fmaf(hv, w.y, a1);
    a2 = fmaf(hv, w.z, a2);
    a3 = fmaf(hv, w.w, a3);
  }
#pragma unroll
  for (int o = 32; o; o >>= 1) {
    a0 += __shfl_down(a0, o);
    a1 += __shfl_down(a1, o);
    a2 += __shfl_down(a2, o);
    a3 += __shfl_down(a3, o);
  }
  if (lane == 0) {
    const float l0 = a0 + b3[0], l1 = a1 + b3[1], l2 = a2 + b3[2], l3 = a3 + b3[3];
    const float m = fmaxf(fmaxf(l0, l1), fmaxf(l2, l3));
    const float e0 = expf(l0 - m), e1 = expf(l1 - m), e2 = expf(l2 - m), e3 = expf(l3 - m);
    const float ls = logf(e0 + e1 + e2 + e3);
    float4 lp;
    lp.x = l0 - m - ls;
    lp.y = l1 - m - ls;
    lp.z = l2 - m - ls;
    lp.w = l3 - m - ls;
    *(float4*)&logp[row * 4] = lp;
  }
}

// ---------------------------------------------------------------------------
// log of multinomial coefficients
// ---------------------------------------------------------------------------
__global__ void log_coeffs(const float* __restrict__ coeffs, float* __restrict__ lc) {
  const int v = blockIdx.x * 256 + threadIdx.x;
  if (v < VV) lc[v] = logf(coeffs[v]);
}

// ---------------------------------------------------------------------------
// Middle: per row b -> logits over V count vectors, Gumbel-softmax (tau=.01),
// mean_z = (z @ cv)/N.  One block (256 thr) per row; scores stashed in LDS.
// ---------------------------------------------------------------------------
__global__ __launch_bounds__(256) void middle(
    const float* __restrict__ logp, const float* __restrict__ rand_grid,
    const float* __restrict__ cv4, const float* __restrict__ lcoef,
    float* __restrict__ mz) {
  __shared__ float s_s[VV];
  __shared__ float sred[4];
  __shared__ float rs[4][5];

  const int b = blockIdx.x;
  const int tid = threadIdx.x;
  const float4 lp = *(const float4*)&logp[b * 4];
  const float* u = rand_grid + (size_t)b * VV;

  float lmax = -INFINITY;
  for (int v = tid; v < VV; v += 256) {
    const float4 c = *(const float4*)&cv4[v * 4];
    float l = lcoef[v] + c.x * lp.x + c.y * lp.y + c.z * lp.z + c.w * lp.w;
    l = fminf(fmaxf(l, LOG_TINY), 0.0f);               // = log(clip(pmf,tiny,1))
    const float g = -logf(-logf(u[v]));                // Gumbel
    const float sv = (l + g) * TAU_INV;
    s_s[v] = sv;
    lmax = fmaxf(lmax, sv);
  }
#pragma unroll
  for (int o = 32; o; o >>= 1) lmax = fmaxf(lmax, __shfl_down(lmax, o));
  if ((tid & 63) == 0) sred[tid >> 6] = lmax;
  __syncthreads();
  const float M = fmaxf(fmaxf(sred[0], sred[1]), fmaxf(sred[2], sred[3]));

  float sum = 0.f, w0 = 0.f, w1 = 0.f, w2 = 0.f, w3 = 0.f;
  for (int v = tid; v < VV; v += 256) {
    const float e = expf(s_s[v] - M);
    const float4 c = *(const float4*)&cv4[v * 4];
    sum += e;
    w0 = fmaf(e, c.x, w0);
    w1 = fmaf(e, c.y, w1);
    w2 = fmaf(e, c.z, w2);
    w3 = fmaf(e, c.w, w3);
  }
#pragma unroll
  for (int o = 32; o; o >>= 1) {
    sum += __shfl_down(sum, o);
    w0 += __shfl_down(w0, o);
    w1 += __shfl_down(w1, o);
    w2 += __shfl_down(w2, o);
    w3 += __shfl_down(w3, o);
  }
  if ((tid & 63) == 0) {
    const int w = tid >> 6;
    rs[w][0] = sum; rs[w][1] = w0; rs[w][2] = w1; rs[w][3] = w2; rs[w][4] = w3;
  }
  __syncthreads();
  if (tid == 0) {
    const float S = rs[0][0] + rs[1][0] + rs[2][0] + rs[3][0];
    const float inv = 1.0f / (S * (float)NTRIAL);
    float4 o;
    o.x = (rs[0][1] + rs[1][1] + rs[2][1] + rs[3][1]) * inv;
    o.y = (rs[0][2] + rs[1][2] + rs[2][2] + rs[3][2]) * inv;
    o.z = (rs[0][3] + rs[1][3] + rs[2][3] + rs[3][3]) * inv;
    o.w = (rs[0][4] + rs[1][4] + rs[2][4] + rs[3][4]) * inv;
    *(float4*)&mz[b * 4] = o;
  }
}

// ---------------------------------------------------------------------------
// Decoder layer 1: h3 = relu(mz @ dec_w1 + b1), mz (B,4), dec_w1 (4,H).
// One block per row, each thread 4 contiguous outputs.
// ---------------------------------------------------------------------------
__global__ __launch_bounds__(256) void dec1(
    const float* __restrict__ mz, const float* __restrict__ w1,
    const float* __restrict__ b1, float* __restrict__ h3) {
  const int b = blockIdx.x;
  const int j = threadIdx.x << 2;
  const float4 m = *(const float4*)&mz[b * 4];
  float4 acc = *(const float4*)&b1[j];
  const float4 q0 = *(const float4*)&w1[j];
  const float4 q1 = *(const float4*)&w1[HH + j];
  const float4 q2 = *(const float4*)&w1[2 * HH + j];
  const float4 q3 = *(const float4*)&w1[3 * HH + j];
  acc.x = fmaf(m.x, q0.x, fmaf(m.y, q1.x, fmaf(m.z, q2.x, fmaf(m.w, q3.x, acc.x))));
  acc.y = fmaf(m.x, q0.y, fmaf(m.y, q1.y, fmaf(m.z, q2.y, fmaf(m.w, q3.y, acc.y))));
  acc.z = fmaf(m.x, q0.z, fmaf(m.y, q1.z, fmaf(m.z, q2.z, fmaf(m.w, q3.z, acc.z))));
  acc.w = fmaf(m.x, q0.w, fmaf(m.y, q1.w, fmaf(m.z, q2.w, fmaf(m.w, q3.w, acc.w))));
  acc.x = fmaxf(acc.x, 0.f);
  acc.y = fmaxf(acc.y, 0.f);
  acc.z = fmaxf(acc.z, 0.f);
  acc.w = fmaxf(acc.w, 0.f);
  *(float4*)&h3[(size_t)b * HH + j] = acc;
}

// ---------------------------------------------------------------------------
// Buffer ping-pong uses d_out as one of the two big activation buffers so the
// workspace requirement is only ~16.1 MB:
//   h1 -> OUT, h2 -> WS, logp/mz/lcoef -> WS(small), h3 -> OUT, h4 -> WS,
//   final -> OUT.  Every kernel reads one buffer and writes the other.
// ---------------------------------------------------------------------------
extern "C" void kernel_launch(void* const* d_in, const int* in_sizes, int n_in,
                              void* d_out, int out_size, void* d_ws, size_t ws_size,
                              hipStream_t stream) {
  const float* x       = (const float*)d_in[0];
  const float* rand_g  = (const float*)d_in[1];
  const float* enc_w1  = (const float*)d_in[2];
  const float* enc_b1  = (const float*)d_in[3];
  const float* enc_w2  = (const float*)d_in[4];
  const float* enc_b2  = (const float*)d_in[5];
  const float* enc_w3  = (const float*)d_in[6];
  const float* enc_b3  = (const float*)d_in[7];
  const float* dec_w1  = (const float*)d_in[8];
  const float* dec_b1  = (const float*)d_in[9];
  const float* dec_w2  = (const float*)d_in[10];
  const float* dec_b2  = (const float*)d_in[11];
  const float* dec_w3  = (const float*)d_in[12];
  const float* dec_b3  = (const float*)d_in[13];
  const float* cv4     = (const float*)d_in[14];
  const float* coeffs  = (const float*)d_in[15];
  float* out = (float*)d_out;

  float* ws = (float*)d_ws;
  float* bufW  = ws;                       // h2, later h4   (4096*1024)
  float* logp  = bufW + (size_t)BB * HH;   // (B,4)
  float* mzp   = logp + BB * 4;            // (B,4)
  float* lcoef = mzp + BB * 4;             // (V)

  const dim3 gemm_grid(HH / BN, BB / BM);  // (8, 32)

  log_coeffs<<<(VV + 255) / 256, 256, 0, stream>>>(coeffs, lcoef);

  // encoder: h1 -> OUT, h2 -> WS
  gemm_rowrow<true><<<gemm_grid, 256, 0, stream>>>(x, enc_w1, enc_b1, out, BB, HH, DD);
  gemm_rowrow<true><<<gemm_grid, 256, 0, stream>>>(out, enc_w2, enc_b2, bufW, BB, HH, HH);
  enc_head<<<BB / 4, 256, 0, stream>>>(bufW, enc_w3, enc_b3, logp);

  // gumbel-softmax over count vectors
  middle<<<BB, 256, 0, stream>>>(logp, rand_g, cv4, lcoef, mzp);

  // decoder: h3 -> OUT, h4 -> WS, final -> OUT
  dec1<<<BB, 256, 0, stream>>>(mzp, dec_w1, dec_b1, out);
  gemm_rowrow<true><<<gemm_grid, 256, 0, stream>>>(out, dec_w2, dec_b2, bufW, BB, HH, HH);
  gemm_rowrow<false><<<dim3(DD / BN, BB / BM), 256, 0, stream>>>(bufW, dec_w3, dec_b3, out, BB, DD, HH);
}

// Round 3
// 611.915 us; speedup vs baseline: 4.7752x; 4.7752x over previous
//
#include <hip/hip_runtime.h>
#include <hip/hip_bf16.h>
#include <cstdint>

// Problem constants (Multinomial VAE)
#define BB 4096
#define DD 1024
#define HH 1024
#define NTRIAL 24
#define VV 2925
#define TAU_INV 100.0f
#define LOG_TINY -87.336544750402f  // logf(1.17549435e-38f)

typedef unsigned int uint;
typedef unsigned short ushort;
typedef __attribute__((ext_vector_type(8))) short short8v;  // 8 bf16 (4 VGPRs)
typedef __attribute__((ext_vector_type(4))) float f32x4;

// bf16 helpers (RNE)
__device__ __forceinline__ ushort f2bf(float f) {
  uint u = __float_as_uint(f);
  uint r = u + 0x7fffu + ((u >> 16) & 1u);
  return (ushort)(r >> 16);
}
__device__ __forceinline__ float bf2f(ushort h) {
  return __uint_as_float(((uint)h) << 16);
}

// ---------------------------------------------------------------------------
// fp32 GEMM (encoder): C = relu(A @ W + bias). M=4096, N=K=1024 hardcoded.
// 128x128 tile, BK=16, 256 thr, 8x8/thread with NAMED float4 accumulators
// (previous version spilled: WRITE_SIZE 1.85 GB of scratch, VALUBusy 8%).
// ---------------------------------------------------------------------------
#define BM 128
#define BN 128
#define BK 16
#define PAD 4

#define FMAROW(CA, CB, AV)                                     \
  CA.x = fmaf(AV, b0.x, CA.x); CA.y = fmaf(AV, b0.y, CA.y);    \
  CA.z = fmaf(AV, b0.z, CA.z); CA.w = fmaf(AV, b0.w, CA.w);    \
  CB.x = fmaf(AV, b1.x, CB.x); CB.y = fmaf(AV, b1.y, CB.y);    \
  CB.z = fmaf(AV, b1.z, CB.z); CB.w = fmaf(AV, b1.w, CB.w);

template <bool RELU>
__global__ __launch_bounds__(256, 1) void gemm_f32(
    const float* __restrict__ A, const float* __restrict__ W,
    const float* __restrict__ bias, float* __restrict__ C) {
  __shared__ float As[2][BK][BM + PAD];
  __shared__ float Bs[2][BK][BN + PAD];

  const int tid = threadIdx.x;
  const int m0 = blockIdx.y * BM;
  const int n0 = blockIdx.x * BN;
  const int tr = tid >> 4;
  const int tc = tid & 15;

  const int arow = tid >> 2;
  const int acol = (tid & 3) << 2;
  const int brow = tid >> 5;
  const int bcol = (tid & 31) << 2;

  const float* Ap0 = A + (size_t)(m0 + arow) * 1024 + acol;
  const float* Ap1 = Ap0 + (size_t)64 * 1024;
  const float* Wp0 = W + (size_t)brow * 1024 + n0 + bcol;
  const float* Wp1 = Wp0 + (size_t)8 * 1024;

  float4 ra0 = *(const float4*)Ap0;
  float4 ra1 = *(const float4*)Ap1;
  float4 rb0 = *(const float4*)Wp0;
  float4 rb1 = *(const float4*)Wp1;

  float4 c00 = {0,0,0,0}, c01 = {0,0,0,0}, c10 = {0,0,0,0}, c11 = {0,0,0,0};
  float4 c20 = {0,0,0,0}, c21 = {0,0,0,0}, c30 = {0,0,0,0}, c31 = {0,0,0,0};
  float4 c40 = {0,0,0,0}, c41 = {0,0,0,0}, c50 = {0,0,0,0}, c51 = {0,0,0,0};
  float4 c60 = {0,0,0,0}, c61 = {0,0,0,0}, c70 = {0,0,0,0}, c71 = {0,0,0,0};

  // write tile 0
  As[0][acol + 0][arow] = ra0.x;
  As[0][acol + 1][arow] = ra0.y;
  As[0][acol + 2][arow] = ra0.z;
  As[0][acol + 3][arow] = ra0.w;
  As[0][acol + 0][arow + 64] = ra1.x;
  As[0][acol + 1][arow + 64] = ra1.y;
  As[0][acol + 2][arow + 64] = ra1.z;
  As[0][acol + 3][arow + 64] = ra1.w;
  *(float4*)&Bs[0][brow][bcol] = rb0;
  *(float4*)&Bs[0][brow + 8][bcol] = rb1;
  __syncthreads();

  int cur = 0;
#pragma unroll 1
  for (int kt = 0; kt < 1024 / BK; ++kt) {
    const bool more = (kt + 1 < 1024 / BK);
    if (more) {
      Ap0 += BK; Ap1 += BK;
      Wp0 += (size_t)BK * 1024; Wp1 += (size_t)BK * 1024;
      ra0 = *(const float4*)Ap0;
      ra1 = *(const float4*)Ap1;
      rb0 = *(const float4*)Wp0;
      rb1 = *(const float4*)Wp1;
    }
#pragma unroll
    for (int kk = 0; kk < BK; ++kk) {
      const float4 a0 = *(const float4*)&As[cur][kk][tr * 8];
      const float4 a1 = *(const float4*)&As[cur][kk][tr * 8 + 4];
      const float4 b0 = *(const float4*)&Bs[cur][kk][tc * 4];
      const float4 b1 = *(const float4*)&Bs[cur][kk][tc * 4 + 64];
      FMAROW(c00, c01, a0.x)
      FMAROW(c10, c11, a0.y)
      FMAROW(c20, c21, a0.z)
      FMAROW(c30, c31, a0.w)
      FMAROW(c40, c41, a1.x)
      FMAROW(c50, c51, a1.y)
      FMAROW(c60, c61, a1.z)
      FMAROW(c70, c71, a1.w)
    }
    if (more) {
      const int nxt = cur ^ 1;
      As[nxt][acol + 0][arow] = ra0.x;
      As[nxt][acol + 1][arow] = ra0.y;
      As[nxt][acol + 2][arow] = ra0.z;
      As[nxt][acol + 3][arow] = ra0.w;
      As[nxt][acol + 0][arow + 64] = ra1.x;
      As[nxt][acol + 1][arow + 64] = ra1.y;
      As[nxt][acol + 2][arow + 64] = ra1.z;
      As[nxt][acol + 3][arow + 64] = ra1.w;
      *(float4*)&Bs[nxt][brow][bcol] = rb0;
      *(float4*)&Bs[nxt][brow + 8][bcol] = rb1;
      __syncthreads();
      cur = nxt;
    }
  }

  const float4 bb0 = *(const float4*)&bias[n0 + tc * 4];
  const float4 bb1 = *(const float4*)&bias[n0 + 64 + tc * 4];
#define EPI(CA, CB, i)                                               \
  {                                                                  \
    float* Cp = C + (size_t)(m0 + tr * 8 + i) * 1024 + n0;           \
    float4 o0 = CA, o1 = CB;                                         \
    o0.x += bb0.x; o0.y += bb0.y; o0.z += bb0.z; o0.w += bb0.w;      \
    o1.x += bb1.x; o1.y += bb1.y; o1.z += bb1.z; o1.w += bb1.w;      \
    if (RELU) {                                                      \
      o0.x = fmaxf(o0.x, 0.f); o0.y = fmaxf(o0.y, 0.f);              \
      o0.z = fmaxf(o0.z, 0.f); o0.w = fmaxf(o0.w, 0.f);              \
      o1.x = fmaxf(o1.x, 0.f); o1.y = fmaxf(o1.y, 0.f);              \
      o1.z = fmaxf(o1.z, 0.f); o1.w = fmaxf(o1.w, 0.f);              \
    }                                                                \
    *(float4*)&Cp[tc * 4] = o0;                                      \
    *(float4*)&Cp[64 + tc * 4] = o1;                                 \
  }
  EPI(c00, c01, 0) EPI(c10, c11, 1) EPI(c20, c21, 2) EPI(c30, c31, 3)
  EPI(c40, c41, 4) EPI(c50, c51, 5) EPI(c60, c61, 6) EPI(c70, c71, 7)
#undef EPI
}

// ---------------------------------------------------------------------------
// MFMA bf16x2-split GEMM (decoder): C = act(A@W + bias), fp32-equivalent via
// 3 products Ahi*Whi + Alo*Whi + Ahi*Wlo mapped to a virtual K=3072.
//   Ahl: (4096, 2048) bf16, cols [0,1024)=hi, [1024,2048)=lo  (k-fastest)
//   Wt:  (1024, 2048) bf16, row n, cols = k of W^T; [0,1024)=hi, [1024,2048)=lo
// 128x128 tile, BK=32, 4 waves each computing 64x64 (4x4 frags of 16x16x32).
// ---------------------------------------------------------------------------
template <bool RELU>
__global__ __launch_bounds__(256, 1) void mfma_gemm(
    const ushort* __restrict__ Ahl, const ushort* __restrict__ Wt,
    const float* __restrict__ bias, float* __restrict__ C) {
  __shared__ ushort As[2][128 * 32];
  __shared__ ushort Bs[2][128 * 32];

  const int t = threadIdx.x;
  const int m0 = blockIdx.y * 128;
  const int n0 = blockIdx.x * 128;
  const int wv = t >> 6, lane = t & 63;
  const int wr = wv >> 1, wc = wv & 1;
  const int lrow = lane & 15, lk = lane >> 4;

  const int arow = t >> 2;            // staging row 0..63
  const int achunk = (t & 3) * 8;     // ushort offset within 32-elem row

  f32x4 acc[4][4] = {};

  auto STAGE = [&](int b, int kt) {
    const int p = kt >> 5;                 // product: 0 hi*hi, 1 lo*hi, 2 hi*lo
    const int k0 = (kt & 31) * 32;
    const int aoff = (p == 1) ? 1024 : 0;  // A lo for product 1
    const int woff = (p == 2) ? 1024 : 0;  // W lo for product 2
    const ushort* Ap = Ahl + (size_t)(m0 + arow) * 2048 + aoff + k0 + achunk;
    const ushort* Bp = Wt + (size_t)(n0 + arow) * 2048 + woff + k0 + achunk;
    const uint4 va0 = *(const uint4*)Ap;
    const uint4 va1 = *(const uint4*)(Ap + (size_t)64 * 2048);
    const uint4 vb0 = *(const uint4*)Bp;
    const uint4 vb1 = *(const uint4*)(Bp + (size_t)64 * 2048);
    *(uint4*)&As[b][t * 8] = va0;
    *(uint4*)&As[b][64 * 32 + t * 8] = va1;
    *(uint4*)&Bs[b][t * 8] = vb0;
    *(uint4*)&Bs[b][64 * 32 + t * 8] = vb1;
  };

  STAGE(0, 0);
  __syncthreads();
  int cur = 0;
#pragma unroll 2
  for (int kt = 0; kt < 96; ++kt) {
    if (kt + 1 < 96) STAGE(cur ^ 1, kt + 1);
    const ushort* as = As[cur];
    const ushort* bs = Bs[cur];
    short8v af[4], bf[4];
#pragma unroll
    for (int i = 0; i < 4; ++i)
      af[i] = *(const short8v*)&as[(wr * 64 + i * 16 + lrow) * 32 + lk * 8];
#pragma unroll
    for (int j = 0; j < 4; ++j)
      bf[j] = *(const short8v*)&bs[(wc * 64 + j * 16 + lrow) * 32 + lk * 8];
#pragma unroll
    for (int i = 0; i < 4; ++i)
#pragma unroll
      for (int j = 0; j < 4; ++j)
        acc[i][j] = __builtin_amdgcn_mfma_f32_16x16x32_bf16(af[i], bf[j], acc[i][j], 0, 0, 0);
    __syncthreads();
    cur ^= 1;
  }

  // epilogue: D row = (lane>>4)*4 + q, col = lane&15 (m89-verified layout)
#pragma unroll
  for (int j = 0; j < 4; ++j) {
    const int c = n0 + wc * 64 + j * 16 + lrow;
    const float bv = bias[c];
#pragma unroll
    for (int i = 0; i < 4; ++i) {
#pragma unroll
      for (int q = 0; q < 4; ++q) {
        const int r = m0 + wr * 64 + i * 16 + lk * 4 + q;
        float v = acc[i][j][q] + bv;
        if (RELU) v = fmaxf(v, 0.f);
        C[(size_t)r * 1024 + c] = v;
      }
    }
  }
}

// ---------------------------------------------------------------------------
// Activation split: fp32 (4096,1024) -> bf16 hi/lo packed (4096,2048)
// ---------------------------------------------------------------------------
__global__ __launch_bounds__(256) void asplit(const float* __restrict__ in,
                                              ushort* __restrict__ o) {
  const int i4 = (blockIdx.x * 256 + threadIdx.x) * 4;
  const float4 v = *(const float4*)&in[i4];
  const int row = i4 >> 10, col = i4 & 1023;
  ushort h0 = f2bf(v.x), h1 = f2bf(v.y), h2 = f2bf(v.z), h3 = f2bf(v.w);
  ushort l0 = f2bf(v.x - bf2f(h0)), l1 = f2bf(v.y - bf2f(h1));
  ushort l2 = f2bf(v.z - bf2f(h2)), l3 = f2bf(v.w - bf2f(h3));
  uint2 hp, lp;
  hp.x = (uint)h0 | ((uint)h1 << 16); hp.y = (uint)h2 | ((uint)h3 << 16);
  lp.x = (uint)l0 | ((uint)l1 << 16); lp.y = (uint)l2 | ((uint)l3 << 16);
  *(uint2*)&o[(size_t)row * 2048 + col] = hp;
  *(uint2*)&o[(size_t)row * 2048 + 1024 + col] = lp;
}

// ---------------------------------------------------------------------------
// Weight split + transpose: W (1024,1024) [k][n] -> Wt (1024,2048) [n][k hi|lo]
// ---------------------------------------------------------------------------
__global__ __launch_bounds__(256) void wsplit_t(const float* __restrict__ W,
                                                ushort* __restrict__ Wt) {
  __shared__ float tile[32][33];
  const int bx = blockIdx.x, by = blockIdx.y;
  const int tx = threadIdx.x, ty = threadIdx.y;
#pragma unroll
  for (int r = ty; r < 32; r += 8)
    tile[r][tx] = W[(size_t)(by * 32 + r) * 1024 + bx * 32 + tx];
  __syncthreads();
#pragma unroll
  for (int r = ty; r < 32; r += 8) {
    const float v = tile[tx][r];  // = W[by*32+tx][bx*32+r]
    const ushort hi = f2bf(v);
    const ushort lo = f2bf(v - bf2f(hi));
    const size_t n = bx * 32 + r, k = by * 32 + tx;
    Wt[n * 2048 + k] = hi;
    Wt[n * 2048 + 1024 + k] = lo;
  }
}

// ---------------------------------------------------------------------------
// Encoder head: logits = h2 @ enc_w3 + b3 -> log-softmax (4 classes)
// ---------------------------------------------------------------------------
__global__ __launch_bounds__(256) void enc_head(
    const float* __restrict__ h2, const float* __restrict__ w3,
    const float* __restrict__ b3, float* __restrict__ logp) {
  const int wave = threadIdx.x >> 6;
  const int lane = threadIdx.x & 63;
  const int row = blockIdx.x * 4 + wave;
  const float* h = h2 + (size_t)row * HH;
  float a0 = 0.f, a1 = 0.f, a2 = 0.f, a3 = 0.f;
#pragma unroll
  for (int k = lane; k < HH; k += 64) {
    const float hv = h[k];
    const float4 w = *(const float4*)&w3[k * 4];
    a0 = fmaf(hv, w.x, a0);
    a1 = fmaf(hv, w.y, a1);
    a2 = fmaf(hv, w.z, a2);
    a3 = fmaf(hv, w.w, a3);
  }
#pragma unroll
  for (int o = 32; o; o >>= 1) {
    a0 += __shfl_down(a0, o);
    a1 += __shfl_down(a1, o);
    a2 += __shfl_down(a2, o);
    a3 += __shfl_down(a3, o);
  }
  if (lane == 0) {
    const float l0 = a0 + b3[0], l1 = a1 + b3[1], l2 = a2 + b3[2], l3 = a3 + b3[3];
    const float m = fmaxf(fmaxf(l0, l1), fmaxf(l2, l3));
    const float e0 = expf(l0 - m), e1 = expf(l1 - m), e2 = expf(l2 - m), e3 = expf(l3 - m);
    const float ls = logf(e0 + e1 + e2 + e3);
    float4 lp;
    lp.x = l0 - m - ls;
    lp.y = l1 - m - ls;
    lp.z = l2 - m - ls;
    lp.w = l3 - m - ls;
    *(float4*)&logp[row * 4] = lp;
  }
}

__global__ void log_coeffs(const float* __restrict__ coeffs, float* __restrict__ lc) {
  const int v = blockIdx.x * 256 + threadIdx.x;
  if (v < VV) lc[v] = logf(coeffs[v]);
}

// ---------------------------------------------------------------------------
// Gumbel-softmax over count vectors -> mean_z. One block (256 thr) per row.
// ---------------------------------------------------------------------------
__global__ __launch_bounds__(256) void middle(
    const float* __restrict__ logp, const float* __restrict__ rand_grid,
    const float* __restrict__ cv4, const float* __restrict__ lcoef,
    float* __restrict__ mz) {
  __shared__ float s_s[VV];
  __shared__ float sred[4];
  __shared__ float rs[4][5];

  const int b = blockIdx.x;
  const int tid = threadIdx.x;
  const float4 lp = *(const float4*)&logp[b * 4];
  const float* u = rand_grid + (size_t)b * VV;

  float lmax = -INFINITY;
  for (int v = tid; v < VV; v += 256) {
    const float4 c = *(const float4*)&cv4[v * 4];
    float l = lcoef[v] + c.x * lp.x + c.y * lp.y + c.z * lp.z + c.w * lp.w;
    l = fminf(fmaxf(l, LOG_TINY), 0.0f);
    const float g = -logf(-logf(u[v]));
    const float sv = (l + g) * TAU_INV;
    s_s[v] = sv;
    lmax = fmaxf(lmax, sv);
  }
#pragma unroll
  for (int o = 32; o; o >>= 1) lmax = fmaxf(lmax, __shfl_down(lmax, o));
  if ((tid & 63) == 0) sred[tid >> 6] = lmax;
  __syncthreads();
  const float M = fmaxf(fmaxf(sred[0], sred[1]), fmaxf(sred[2], sred[3]));

  float sum = 0.f, w0 = 0.f, w1 = 0.f, w2 = 0.f, w3 = 0.f;
  for (int v = tid; v < VV; v += 256) {
    const float e = expf(s_s[v] - M);
    const float4 c = *(const float4*)&cv4[v * 4];
    sum += e;
    w0 = fmaf(e, c.x, w0);
    w1 = fmaf(e, c.y, w1);
    w2 = fmaf(e, c.z, w2);
    w3 = fmaf(e, c.w, w3);
  }
#pragma unroll
  for (int o = 32; o; o >>= 1) {
    sum += __shfl_down(sum, o);
    w0 += __shfl_down(w0, o);
    w1 += __shfl_down(w1, o);
    w2 += __shfl_down(w2, o);
    w3 += __shfl_down(w3, o);
  }
  if ((tid & 63) == 0) {
    const int w = tid >> 6;
    rs[w][0] = sum; rs[w][1] = w0; rs[w][2] = w1; rs[w][3] = w2; rs[w][4] = w3;
  }
  __syncthreads();
  if (tid == 0) {
    const float S = rs[0][0] + rs[1][0] + rs[2][0] + rs[3][0];
    const float inv = 1.0f / (S * (float)NTRIAL);
    float4 o;
    o.x = (rs[0][1] + rs[1][1] + rs[2][1] + rs[3][1]) * inv;
    o.y = (rs[0][2] + rs[1][2] + rs[2][2] + rs[3][2]) * inv;
    o.z = (rs[0][3] + rs[1][3] + rs[2][3] + rs[3][3]) * inv;
    o.w = (rs[0][4] + rs[1][4] + rs[2][4] + rs[3][4]) * inv;
    *(float4*)&mz[b * 4] = o;
  }
}

// ---------------------------------------------------------------------------
// Decoder layer 1: h3 = relu(mz @ dec_w1 + b1); (B,4)x(4,H)
// ---------------------------------------------------------------------------
__global__ __launch_bounds__(256) void dec1(
    const float* __restrict__ mz, const float* __restrict__ w1,
    const float* __restrict__ b1, float* __restrict__ h3) {
  const int b = blockIdx.x;
  const int j = threadIdx.x << 2;
  const float4 m = *(const float4*)&mz[b * 4];
  float4 acc = *(const float4*)&b1[j];
  const float4 q0 = *(const float4*)&w1[j];
  const float4 q1 = *(const float4*)&w1[HH + j];
  const float4 q2 = *(const float4*)&w1[2 * HH + j];
  const float4 q3 = *(const float4*)&w1[3 * HH + j];
  acc.x = fmaf(m.x, q0.x, fmaf(m.y, q1.x, fmaf(m.z, q2.x, fmaf(m.w, q3.x, acc.x))));
  acc.y = fmaf(m.x, q0.y, fmaf(m.y, q1.y, fmaf(m.z, q2.y, fmaf(m.w, q3.y, acc.y))));
  acc.z = fmaf(m.x, q0.z, fmaf(m.y, q1.z, fmaf(m.z, q2.z, fmaf(m.w, q3.z, acc.z))));
  acc.w = fmaf(m.x, q0.w, fmaf(m.y, q1.w, fmaf(m.z, q2.w, fmaf(m.w, q3.w, acc.w))));
  acc.x = fmaxf(acc.x, 0.f);
  acc.y = fmaxf(acc.y, 0.f);
  acc.z = fmaxf(acc.z, 0.f);
  acc.w = fmaxf(acc.w, 0.f);
  *(float4*)&h3[(size_t)b * HH + j] = acc;
}

// ---------------------------------------------------------------------------
// ws layout (40.3 MB): bufW fp32 16MB | Asp bf16 16MB | Wt2 4MB | Wt3 4MB |
// logp/mz/lcoef. d_out is the second big fp32 buffer (h1, h3, final).
// ---------------------------------------------------------------------------
extern "C" void kernel_launch(void* const* d_in, const int* in_sizes, int n_in,
                              void* d_out, int out_size, void* d_ws, size_t ws_size,
                              hipStream_t stream) {
  const float* x      = (const float*)d_in[0];
  const float* rand_g = (const float*)d_in[1];
  const float* enc_w1 = (const float*)d_in[2];
  const float* enc_b1 = (const float*)d_in[3];
  const float* enc_w2 = (const float*)d_in[4];
  const float* enc_b2 = (const float*)d_in[5];
  const float* enc_w3 = (const float*)d_in[6];
  const float* enc_b3 = (const float*)d_in[7];
  const float* dec_w1 = (const float*)d_in[8];
  const float* dec_b1 = (const float*)d_in[9];
  const float* dec_w2 = (const float*)d_in[10];
  const float* dec_b2 = (const float*)d_in[11];
  const float* dec_w3 = (const float*)d_in[12];
  const float* dec_b3 = (const float*)d_in[13];
  const float* cv4    = (const float*)d_in[14];
  const float* coeffs = (const float*)d_in[15];
  float* out = (float*)d_out;

  float* ws = (float*)d_ws;
  float* bufW   = ws;                                   // h2, then h4 (fp32)
  ushort* Asp   = (ushort*)(ws + (size_t)BB * HH);      // activation hi|lo
  ushort* Wt2   = Asp + (size_t)BB * 2048;              // dec_w2^T hi|lo
  ushort* Wt3   = Wt2 + (size_t)1024 * 2048;            // dec_w3^T hi|lo
  float*  logp  = (float*)(Wt3 + (size_t)1024 * 2048);
  float*  mzp   = logp + BB * 4;
  float*  lcoef = mzp + BB * 4;

  const dim3 gemm_grid(1024 / BN, BB / BM);  // (8, 32)
  const dim3 wt_grid(32, 32), wt_blk(32, 8);

  log_coeffs<<<(VV + 255) / 256, 256, 0, stream>>>(coeffs, lcoef);
  wsplit_t<<<wt_grid, wt_blk, 0, stream>>>(dec_w2, Wt2);
  wsplit_t<<<wt_grid, wt_blk, 0, stream>>>(dec_w3, Wt3);

  // encoder (fp32, bit-identical argmax path): h1 -> OUT, h2 -> WS
  gemm_f32<true><<<gemm_grid, 256, 0, stream>>>(x, enc_w1, enc_b1, out);
  gemm_f32<true><<<gemm_grid, 256, 0, stream>>>(out, enc_w2, enc_b2, bufW);
  enc_head<<<BB / 4, 256, 0, stream>>>(bufW, enc_w3, enc_b3, logp);

  middle<<<BB, 256, 0, stream>>>(logp, rand_g, cv4, lcoef, mzp);

  // decoder: h3 -> OUT (fp32), split, MFMA GEMMs
  dec1<<<BB, 256, 0, stream>>>(mzp, dec_w1, dec_b1, out);
  asplit<<<(BB * HH) / 1024, 256, 0, stream>>>(out, Asp);
  mfma_gemm<true><<<gemm_grid, 256, 0, stream>>>(Asp, Wt2, dec_b2, bufW);
  asplit<<<(BB * HH) / 1024, 256, 0, stream>>>(bufW, Asp);
  mfma_gemm<false><<<gemm_grid, 256, 0, stream>>>(Asp, Wt3, dec_b3, out);
}

// Round 4
// 479.860 us; speedup vs baseline: 6.0893x; 1.2752x over previous
//
#include <hip/hip_runtime.h>
#include <hip/hip_bf16.h>
#include <cstdint>

// Problem constants (Multinomial VAE)
#define BB 4096
#define DD 1024
#define HH 1024
#define NTRIAL 24
#define VV 2925
#define TAU_INV 100.0f
#define LOG_TINY -87.336544750402f  // logf(1.17549435e-38f)

typedef unsigned int uint;
typedef unsigned short ushort;
typedef __attribute__((ext_vector_type(8))) short short8v;  // 8 bf16 (4 VGPRs)
typedef __attribute__((ext_vector_type(4))) float f32x4;

// bf16 helpers (RNE)
__device__ __forceinline__ ushort f2bf(float f) {
  uint u = __float_as_uint(f);
  uint r = u + 0x7fffu + ((u >> 16) & 1u);
  return (ushort)(r >> 16);
}
__device__ __forceinline__ float bf2f(ushort h) {
  return __uint_as_float(((uint)h) << 16);
}

// ---------------------------------------------------------------------------
// MFMA bf16x2-split GEMM: C = act(A@W + bias), fp32-grade via 3 products
// Ahi*Whi + Alo*Whi + Ahi*Wlo (virtual K = 3072; missing lo*lo ~ 2^-18 rel).
//   Ahl: (4096, 2048) bf16, cols [0,1024)=hi, [1024,2048)=lo (k-fastest)
//   Wt:  (1024, 2048) bf16, row n holds W^T[n][k]; [0,1024)=hi, [1024,2048)=lo
// Tile 128x64, BK=32, 512 wgs (2/CU for inter-block latency hiding at
// barriers; 128^2 gave only 1 wg/CU at N=1024). 4 waves, each 64x32 out
// (4x2 frags of 16x16x32), double-buffered LDS (24 KB).
// OUT_HL: epilogue writes hi/lo bf16 pair (4096,2048) for the next GEMM;
// else fp32 (4096,1024).
// ---------------------------------------------------------------------------
template <bool RELU, bool OUT_HL>
__global__ __launch_bounds__(256, 2) void mfma_gemm(
    const ushort* __restrict__ Ahl, const ushort* __restrict__ Wt,
    const float* __restrict__ bias, void* __restrict__ Cout) {
  __shared__ ushort As[2][128 * 32];
  __shared__ ushort Bs[2][64 * 32];

  const int t = threadIdx.x;
  const int m0 = blockIdx.y * 128;
  const int n0 = blockIdx.x * 64;
  const int wv = t >> 6, lane = t & 63;
  const int wr = wv >> 1, wc = wv & 1;          // wave tile: rows wr*64, cols wc*32
  const int lrow = lane & 15, lk = lane >> 4;   // frag: row/col = lane&15, K-chunk = lane>>4

  const int srow = t >> 2;            // staging row 0..63
  const int schunk = (t & 3) * 8;     // ushort offset within 32-elem row

  f32x4 acc[4][2] = {};

  auto STAGE = [&](int b, int kt) {
    const int p = kt >> 5;                 // product: 0 hi*hi, 1 lo*hi, 2 hi*lo
    const int k0 = (kt & 31) * 32;
    const int aoff = (p == 1) ? 1024 : 0;  // A lo for product 1
    const int woff = (p == 2) ? 1024 : 0;  // W lo for product 2
    const ushort* Ap = Ahl + (size_t)(m0 + srow) * 2048 + aoff + k0 + schunk;
    const ushort* Bp = Wt + (size_t)(n0 + srow) * 2048 + woff + k0 + schunk;
    const uint4 va0 = *(const uint4*)Ap;
    const uint4 va1 = *(const uint4*)(Ap + (size_t)64 * 2048);
    const uint4 vb0 = *(const uint4*)Bp;
    *(uint4*)&As[b][t * 8] = va0;
    *(uint4*)&As[b][64 * 32 + t * 8] = va1;
    *(uint4*)&Bs[b][t * 8] = vb0;
  };

  STAGE(0, 0);
  __syncthreads();
  int cur = 0;
#pragma unroll 2
  for (int kt = 0; kt < 96; ++kt) {
    if (kt + 1 < 96) STAGE(cur ^ 1, kt + 1);
    const ushort* as = As[cur];
    const ushort* bs = Bs[cur];
    short8v af[4], bf[2];
#pragma unroll
    for (int i = 0; i < 4; ++i)
      af[i] = *(const short8v*)&as[(wr * 64 + i * 16 + lrow) * 32 + lk * 8];
#pragma unroll
    for (int j = 0; j < 2; ++j)
      bf[j] = *(const short8v*)&bs[(wc * 32 + j * 16 + lrow) * 32 + lk * 8];
#pragma unroll
    for (int i = 0; i < 4; ++i)
#pragma unroll
      for (int j = 0; j < 2; ++j)
        acc[i][j] = __builtin_amdgcn_mfma_f32_16x16x32_bf16(af[i], bf[j], acc[i][j], 0, 0, 0);
    __syncthreads();
    cur ^= 1;
  }

  // epilogue: D col = lane&15, row = (lane>>4)*4 + q (m89-verified layout)
  ushort* Chl = (ushort*)Cout;
  float* Cf = (float*)Cout;
#pragma unroll
  for (int j = 0; j < 2; ++j) {
    const int c = n0 + wc * 32 + j * 16 + lrow;
    const float bv = bias[c];
#pragma unroll
    for (int i = 0; i < 4; ++i) {
#pragma unroll
      for (int q = 0; q < 4; ++q) {
        const int r = m0 + wr * 64 + i * 16 + lk * 4 + q;
        float v = acc[i][j][q] + bv;
        if (RELU) v = fmaxf(v, 0.f);
        if (OUT_HL) {
          const ushort hi = f2bf(v);
          const ushort lo = f2bf(v - bf2f(hi));
          Chl[(size_t)r * 2048 + c] = hi;
          Chl[(size_t)r * 2048 + 1024 + c] = lo;
        } else {
          Cf[(size_t)r * 1024 + c] = v;
        }
      }
    }
  }
}

// ---------------------------------------------------------------------------
// Activation split: fp32 (4096,1024) -> bf16 hi/lo packed (4096,2048).
// Only needed for the raw input x now (GEMM epilogues fuse the split).
// ---------------------------------------------------------------------------
__global__ __launch_bounds__(256) void asplit(const float* __restrict__ in,
                                              ushort* __restrict__ o) {
  const int i4 = (blockIdx.x * 256 + threadIdx.x) * 4;
  const float4 v = *(const float4*)&in[i4];
  const int row = i4 >> 10, col = i4 & 1023;
  ushort h0 = f2bf(v.x), h1 = f2bf(v.y), h2 = f2bf(v.z), h3 = f2bf(v.w);
  ushort l0 = f2bf(v.x - bf2f(h0)), l1 = f2bf(v.y - bf2f(h1));
  ushort l2 = f2bf(v.z - bf2f(h2)), l3 = f2bf(v.w - bf2f(h3));
  uint2 hp, lp;
  hp.x = (uint)h0 | ((uint)h1 << 16); hp.y = (uint)h2 | ((uint)h3 << 16);
  lp.x = (uint)l0 | ((uint)l1 << 16); lp.y = (uint)l2 | ((uint)l3 << 16);
  *(uint2*)&o[(size_t)row * 2048 + col] = hp;
  *(uint2*)&o[(size_t)row * 2048 + 1024 + col] = lp;
}

// ---------------------------------------------------------------------------
// Weight split + transpose: W (1024,1024) [k][n] -> Wt (1024,2048) [n][k hi|lo]
// ---------------------------------------------------------------------------
__global__ __launch_bounds__(256) void wsplit_t(const float* __restrict__ W,
                                                ushort* __restrict__ Wt) {
  __shared__ float tile[32][33];
  const int bx = blockIdx.x, by = blockIdx.y;
  const int tx = threadIdx.x, ty = threadIdx.y;
#pragma unroll
  for (int r = ty; r < 32; r += 8)
    tile[r][tx] = W[(size_t)(by * 32 + r) * 1024 + bx * 32 + tx];
  __syncthreads();
#pragma unroll
  for (int r = ty; r < 32; r += 8) {
    const float v = tile[tx][r];  // = W[by*32+tx][bx*32+r]
    const ushort hi = f2bf(v);
    const ushort lo = f2bf(v - bf2f(hi));
    const size_t n = bx * 32 + r, k = by * 32 + tx;
    Wt[n * 2048 + k] = hi;
    Wt[n * 2048 + 1024 + k] = lo;
  }
}

// ---------------------------------------------------------------------------
// Encoder head: logits = h2 @ enc_w3 + b3 -> log-softmax (4 classes).
// h2 arrives as hi|lo bf16 (4096,2048); hv = hi+lo (2^-18 rel of fp32).
// ---------------------------------------------------------------------------
__global__ __launch_bounds__(256) void enc_head(
    const ushort* __restrict__ h2hl, const float* __restrict__ w3,
    const float* __restrict__ b3, float* __restrict__ logp) {
  const int wave = threadIdx.x >> 6;
  const int lane = threadIdx.x & 63;
  const int row = blockIdx.x * 4 + wave;
  const ushort* h = h2hl + (size_t)row * 2048;
  float a0 = 0.f, a1 = 0.f, a2 = 0.f, a3 = 0.f;
#pragma unroll
  for (int it = 0; it < 4; ++it) {
    const int k = it * 256 + lane * 4;
    const uint2 hp = *(const uint2*)&h[k];
    const uint2 lp = *(const uint2*)&h[1024 + k];
    float hv[4];
    hv[0] = bf2f((ushort)(hp.x & 0xffff)) + bf2f((ushort)(lp.x & 0xffff));
    hv[1] = bf2f((ushort)(hp.x >> 16)) + bf2f((ushort)(lp.x >> 16));
    hv[2] = bf2f((ushort)(hp.y & 0xffff)) + bf2f((ushort)(lp.y & 0xffff));
    hv[3] = bf2f((ushort)(hp.y >> 16)) + bf2f((ushort)(lp.y >> 16));
#pragma unroll
    for (int jj = 0; jj < 4; ++jj) {
      const float4 w = *(const float4*)&w3[(k + jj) * 4];
      a0 = fmaf(hv[jj], w.x, a0);
      a1 = fmaf(hv[jj], w.y, a1);
      a2 = fmaf(hv[jj], w.z, a2);
      a3 = fmaf(hv[jj], w.w, a3);
    }
  }
#pragma unroll
  for (int o = 32; o; o >>= 1) {
    a0 += __shfl_down(a0, o);
    a1 += __shfl_down(a1, o);
    a2 += __shfl_down(a2, o);
    a3 += __shfl_down(a3, o);
  }
  if (lane == 0) {
    const float l0 = a0 + b3[0], l1 = a1 + b3[1], l2 = a2 + b3[2], l3 = a3 + b3[3];
    const float m = fmaxf(fmaxf(l0, l1), fmaxf(l2, l3));
    const float e0 = expf(l0 - m), e1 = expf(l1 - m), e2 = expf(l2 - m), e3 = expf(l3 - m);
    const float ls = logf(e0 + e1 + e2 + e3);
    float4 lp;
    lp.x = l0 - m - ls;
    lp.y = l1 - m - ls;
    lp.z = l2 - m - ls;
    lp.w = l3 - m - ls;
    *(float4*)&logp[row * 4] = lp;
  }
}

__global__ void log_coeffs(const float* __restrict__ coeffs, float* __restrict__ lc) {
  const int v = blockIdx.x * 256 + threadIdx.x;
  if (v < VV) lc[v] = logf(coeffs[v]);
}

// ---------------------------------------------------------------------------
// Gumbel-softmax over count vectors -> mean_z. One block (256 thr) per row.
// ---------------------------------------------------------------------------
__global__ __launch_bounds__(256) void middle(
    const float* __restrict__ logp, const float* __restrict__ rand_grid,
    const float* __restrict__ cv4, const float* __restrict__ lcoef,
    float* __restrict__ mz) {
  __shared__ float s_s[VV];
  __shared__ float sred[4];
  __shared__ float rs[4][5];

  const int b = blockIdx.x;
  const int tid = threadIdx.x;
  const float4 lp = *(const float4*)&logp[b * 4];
  const float* u = rand_grid + (size_t)b * VV;

  float lmax = -INFINITY;
  for (int v = tid; v < VV; v += 256) {
    const float4 c = *(const float4*)&cv4[v * 4];
    float l = lcoef[v] + c.x * lp.x + c.y * lp.y + c.z * lp.z + c.w * lp.w;
    l = fminf(fmaxf(l, LOG_TINY), 0.0f);
    const float g = -logf(-logf(u[v]));
    const float sv = (l + g) * TAU_INV;
    s_s[v] = sv;
    lmax = fmaxf(lmax, sv);
  }
#pragma unroll
  for (int o = 32; o; o >>= 1) lmax = fmaxf(lmax, __shfl_down(lmax, o));
  if ((tid & 63) == 0) sred[tid >> 6] = lmax;
  __syncthreads();
  const float M = fmaxf(fmaxf(sred[0], sred[1]), fmaxf(sred[2], sred[3]));

  float sum = 0.f, w0 = 0.f, w1 = 0.f, w2 = 0.f, w3 = 0.f;
  for (int v = tid; v < VV; v += 256) {
    const float e = expf(s_s[v] - M);
    const float4 c = *(const float4*)&cv4[v * 4];
    sum += e;
    w0 = fmaf(e, c.x, w0);
    w1 = fmaf(e, c.y, w1);
    w2 = fmaf(e, c.z, w2);
    w3 = fmaf(e, c.w, w3);
  }
#pragma unroll
  for (int o = 32; o; o >>= 1) {
    sum += __shfl_down(sum, o);
    w0 += __shfl_down(w0, o);
    w1 += __shfl_down(w1, o);
    w2 += __shfl_down(w2, o);
    w3 += __shfl_down(w3, o);
  }
  if ((tid & 63) == 0) {
    const int w = tid >> 6;
    rs[w][0] = sum; rs[w][1] = w0; rs[w][2] = w1; rs[w][3] = w2; rs[w][4] = w3;
  }
  __syncthreads();
  if (tid == 0) {
    const float S = rs[0][0] + rs[1][0] + rs[2][0] + rs[3][0];
    const float inv = 1.0f / (S * (float)NTRIAL);
    float4 o;
    o.x = (rs[0][1] + rs[1][1] + rs[2][1] + rs[3][1]) * inv;
    o.y = (rs[0][2] + rs[1][2] + rs[2][2] + rs[3][2]) * inv;
    o.z = (rs[0][3] + rs[1][3] + rs[2][3] + rs[3][3]) * inv;
    o.w = (rs[0][4] + rs[1][4] + rs[2][4] + rs[3][4]) * inv;
    *(float4*)&mz[b * 4] = o;
  }
}

// ---------------------------------------------------------------------------
// Decoder layer 1: h3 = relu(mz @ dec_w1 + b1); (B,4)x(4,H) -> hi/lo bf16.
// ---------------------------------------------------------------------------
__global__ __launch_bounds__(256) void dec1(
    const float* __restrict__ mz, const float* __restrict__ w1,
    const float* __restrict__ b1, ushort* __restrict__ h3hl) {
  const int b = blockIdx.x;
  const int j = threadIdx.x << 2;
  const float4 m = *(const float4*)&mz[b * 4];
  float4 acc = *(const float4*)&b1[j];
  const float4 q0 = *(const float4*)&w1[j];
  const float4 q1 = *(const float4*)&w1[HH + j];
  const float4 q2 = *(const float4*)&w1[2 * HH + j];
  const float4 q3 = *(const float4*)&w1[3 * HH + j];
  acc.x = fmaf(m.x, q0.x, fmaf(m.y, q1.x, fmaf(m.z, q2.x, fmaf(m.w, q3.x, acc.x))));
  acc.y = fmaf(m.x, q0.y, fmaf(m.y, q1.y, fmaf(m.z, q2.y, fmaf(m.w, q3.y, acc.y))));
  acc.z = fmaf(m.x, q0.z, fmaf(m.y, q1.z, fmaf(m.z, q2.z, fmaf(m.w, q3.z, acc.z))));
  acc.w = fmaf(m.x, q0.w, fmaf(m.y, q1.w, fmaf(m.z, q2.w, fmaf(m.w, q3.w, acc.w))));
  acc.x = fmaxf(acc.x, 0.f);
  acc.y = fmaxf(acc.y, 0.f);
  acc.z = fmaxf(acc.z, 0.f);
  acc.w = fmaxf(acc.w, 0.f);
  const ushort h0 = f2bf(acc.x), h1 = f2bf(acc.y), h2 = f2bf(acc.z), h3 = f2bf(acc.w);
  const ushort l0 = f2bf(acc.x - bf2f(h0)), l1 = f2bf(acc.y - bf2f(h1));
  const ushort l2 = f2bf(acc.z - bf2f(h2)), l3 = f2bf(acc.w - bf2f(h3));
  uint2 hp, lp;
  hp.x = (uint)h0 | ((uint)h1 << 16); hp.y = (uint)h2 | ((uint)h3 << 16);
  lp.x = (uint)l0 | ((uint)l1 << 16); lp.y = (uint)l2 | ((uint)l3 << 16);
  *(uint2*)&h3hl[(size_t)b * 2048 + j] = hp;
  *(uint2*)&h3hl[(size_t)b * 2048 + 1024 + j] = lp;
}

// ---------------------------------------------------------------------------
// ws layout (36.2 MB, under the 40.3 MB proven in round 3):
//   H1hl 16MB | H2hl 16MB | Wt 4MB (reused per-GEMM) | logp/mz/lcoef small.
// Xhl (16 MB) lives in d_out (consumed by GEMM1; final GEMM rewrites d_out).
// ---------------------------------------------------------------------------
extern "C" void kernel_launch(void* const* d_in, const int* in_sizes, int n_in,
                              void* d_out, int out_size, void* d_ws, size_t ws_size,
                              hipStream_t stream) {
  const float* x      = (const float*)d_in[0];
  const float* rand_g = (const float*)d_in[1];
  const float* enc_w1 = (const float*)d_in[2];
  const float* enc_b1 = (const float*)d_in[3];
  const float* enc_w2 = (const float*)d_in[4];
  const float* enc_b2 = (const float*)d_in[5];
  const float* enc_w3 = (const float*)d_in[6];
  const float* enc_b3 = (const float*)d_in[7];
  const float* dec_w1 = (const float*)d_in[8];
  const float* dec_b1 = (const float*)d_in[9];
  const float* dec_w2 = (const float*)d_in[10];
  const float* dec_b2 = (const float*)d_in[11];
  const float* dec_w3 = (const float*)d_in[12];
  const float* dec_b3 = (const float*)d_in[13];
  const float* cv4    = (const float*)d_in[14];
  const float* coeffs = (const float*)d_in[15];
  float* out = (float*)d_out;

  ushort* Xhl   = (ushort*)d_out;                      // 4096x2048 = 16 MB exact
  ushort* H1hl  = (ushort*)d_ws;                       // 16 MB
  ushort* H2hl  = H1hl + (size_t)BB * 2048;            // 16 MB
  ushort* Wt    = H2hl + (size_t)BB * 2048;            // 4 MB, reused per GEMM
  float*  logp  = (float*)(Wt + (size_t)1024 * 2048);
  float*  mzp   = logp + BB * 4;
  float*  lcoef = mzp + BB * 4;

  const dim3 mg(1024 / 64, BB / 128);  // (16, 32) = 512 wgs
  const dim3 wt_grid(32, 32), wt_blk(32, 8);

  log_coeffs<<<(VV + 255) / 256, 256, 0, stream>>>(coeffs, lcoef);
  asplit<<<(BB * DD) / 1024, 256, 0, stream>>>(x, Xhl);

  // encoder
  wsplit_t<<<wt_grid, wt_blk, 0, stream>>>(enc_w1, Wt);
  mfma_gemm<true, true><<<mg, 256, 0, stream>>>(Xhl, Wt, enc_b1, H1hl);
  wsplit_t<<<wt_grid, wt_blk, 0, stream>>>(enc_w2, Wt);
  mfma_gemm<true, true><<<mg, 256, 0, stream>>>(H1hl, Wt, enc_b2, H2hl);
  enc_head<<<BB / 4, 256, 0, stream>>>(H2hl, enc_w3, enc_b3, logp);

  // gumbel-softmax over count vectors
  middle<<<BB, 256, 0, stream>>>(logp, rand_g, cv4, lcoef, mzp);

  // decoder (H1hl reused for h3, H2hl for h4)
  dec1<<<BB, 256, 0, stream>>>(mzp, dec_w1, dec_b1, H1hl);
  wsplit_t<<<wt_grid, wt_blk, 0, stream>>>(dec_w2, Wt);
  mfma_gemm<true, true><<<mg, 256, 0, stream>>>(H1hl, Wt, dec_b2, H2hl);
  wsplit_t<<<wt_grid, wt_blk, 0, stream>>>(dec_w3, Wt);
  mfma_gemm<false, false><<<mg, 256, 0, stream>>>(H2hl, Wt, dec_b3, out);
}

// Round 10
// 455.186 us; speedup vs baseline: 6.4194x; 1.0542x over previous
//
#include <hip/hip_runtime.h>
#include <hip/hip_bf16.h>
#include <cstdint>

// Problem constants (Multinomial VAE)
#define BB 4096
#define DD 1024
#define HH 1024
#define NTRIAL 24
#define VV 2925
#define TAU_INV 100.0f
#define LOG_TINY -87.336544750402f  // logf(1.17549435e-38f)

typedef unsigned int uint;
typedef unsigned short ushort;
typedef __attribute__((ext_vector_type(8))) short short8v;  // 8 bf16 (4 VGPRs)
typedef __attribute__((ext_vector_type(4))) float f32x4;

// bf16 helpers (RNE)
__device__ __forceinline__ ushort f2bf(float f) {
  uint u = __float_as_uint(f);
  uint r = u + 0x7fffu + ((u >> 16) & 1u);
  return (ushort)(r >> 16);
}
__device__ __forceinline__ float bf2f(ushort h) {
  return __uint_as_float(((uint)h) << 16);
}

// async global->LDS, 16B per lane; LDS dest must be wave-uniform base
// (HW writes base + lane*16), global src is per-lane.
typedef const __attribute__((address_space(1))) uint g_u32;
typedef __attribute__((address_space(3))) uint l_u32;
__device__ __forceinline__ void gl_lds16(const ushort* g, ushort* l) {
  __builtin_amdgcn_global_load_lds((g_u32*)g, (l_u32*)l, 16, 0, 0);
}

// ---------------------------------------------------------------------------
// MFMA bf16x2-split GEMM: C = act(A@W + bias), fp32-grade via 3 products
// Ahi*Whi + Ahi*Wlo + Alo*Whi (virtual K = 3072; missing lo*lo ~ 2^-18 rel).
//   Ahl: (4096, 2048) bf16, cols [0,1024)=hi, [1024,2048)=lo (k-fastest)
//   Wt:  (1024, 2048) bf16, row n holds W^T[n][k]; [0,1024)=hi, [1024,2048)=lo
// m97-proven structure: 128x128 tile, BK=32, 4 waves, each 64x64 out (4x4
// frags of 16x16x32), double-buffered LDS (32 KB), global_load_lds staging.
// LDS rows are 64B; 16B-chunk XOR swizzle slot^=(row>>1)&3 makes each
// 16-lane phase of the frag read (rows at stride 64B) a free 2-way instead
// of 8-way conflict. Swizzle applied on the GLOBAL source (DMA dest must
// stay linear) and on the ds_read address (both-sides rule #21).
// ---------------------------------------------------------------------------
template <bool RELU, bool OUT_HL>
__global__ __launch_bounds__(256, 1) void mfma_gemm(
    const ushort* __restrict__ Ahl, const ushort* __restrict__ Wt,
    const float* __restrict__ bias, void* __restrict__ Cout) {
  __shared__ ushort As[2][128 * 32];
  __shared__ ushort Bs[2][128 * 32];

  const int t = threadIdx.x;
  const int m0 = blockIdx.y * 128;
  const int n0 = blockIdx.x * 128;
  const int wv = t >> 6, lane = t & 63;
  const int wr = wv >> 1, wc = wv & 1;          // wave tile: rows wr*64, cols wc*64
  const int lrow = lane & 15, lk = lane >> 4;   // frag row/col + K-chunk

  // staging decomposition: wave wv covers tile-rows [wv*32, wv*32+32)
  const int sub = lane >> 2;   // 0..15 row within a 16-row DMA segment
  const int slot = lane & 3;   // 16B slot within the 64B LDS row

  f32x4 acc[4][4] = {};

  auto STAGE = [&](int b, int kt) {
    const int p = kt >> 5;                  // 0: hi*hi, 1: hi*lo, 2: lo*hi
    const int k0 = (kt & 31) * 32;
    const int aoff = (p == 2) ? 1024 : 0;   // A-lo only in product 2
    const int woff = (p == 1) ? 1024 : 0;   // W-lo only in product 1
#pragma unroll
    for (int c = 0; c < 2; ++c) {
      const int row = wv * 32 + c * 16 + sub;
      const int sc = slot ^ ((row >> 1) & 3);  // inverse-swizzled source chunk
      const ushort* gA = Ahl + (size_t)(m0 + row) * 2048 + aoff + k0 + sc * 8;
      const ushort* gB = Wt + (size_t)(n0 + row) * 2048 + woff + k0 + sc * 8;
      gl_lds16(gA, &As[b][(wv * 32 + c * 16) * 32]);
      gl_lds16(gB, &Bs[b][(wv * 32 + c * 16) * 32]);
    }
  };

  STAGE(0, 0);
  __syncthreads();
  int cur = 0;
#pragma unroll 2
  for (int kt = 0; kt < 96; ++kt) {
    if (kt + 1 < 96) STAGE(cur ^ 1, kt + 1);
    const ushort* as = As[cur];
    const ushort* bs = Bs[cur];
    short8v af[4], bf[4];
#pragma unroll
    for (int i = 0; i < 4; ++i) {
      const int row = wr * 64 + i * 16 + lrow;
      af[i] = *(const short8v*)&as[row * 32 + (lk ^ ((row >> 1) & 3)) * 8];
    }
#pragma unroll
    for (int j = 0; j < 4; ++j) {
      const int row = wc * 64 + j * 16 + lrow;
      bf[j] = *(const short8v*)&bs[row * 32 + (lk ^ ((row >> 1) & 3)) * 8];
    }
#pragma unroll
    for (int i = 0; i < 4; ++i)
#pragma unroll
      for (int j = 0; j < 4; ++j)
        acc[i][j] = __builtin_amdgcn_mfma_f32_16x16x32_bf16(af[i], bf[j], acc[i][j], 0, 0, 0);
    __syncthreads();   // drains lgkmcnt (reads done) and vmcnt (DMA done)
    cur ^= 1;
  }

  // epilogue: D col = lane&15, row = (lane>>4)*4 + q (m89-verified layout)
  ushort* Chl = (ushort*)Cout;
  float* Cf = (float*)Cout;
#pragma unroll
  for (int j = 0; j < 4; ++j) {
    const int c = n0 + wc * 64 + j * 16 + lrow;
    const float bv = bias[c];
#pragma unroll
    for (int i = 0; i < 4; ++i) {
#pragma unroll
      for (int q = 0; q < 4; ++q) {
        const int r = m0 + wr * 64 + i * 16 + lk * 4 + q;
        float v = acc[i][j][q] + bv;
        if (RELU) v = fmaxf(v, 0.f);
        if (OUT_HL) {
          const ushort hi = f2bf(v);
          const ushort lo = f2bf(v - bf2f(hi));
          Chl[(size_t)r * 2048 + c] = hi;
          Chl[(size_t)r * 2048 + 1024 + c] = lo;
        } else {
          Cf[(size_t)r * 1024 + c] = v;
        }
      }
    }
  }
}

// ---------------------------------------------------------------------------
// Activation split: fp32 (4096,1024) -> bf16 hi/lo packed (4096,2048).
// Only needed for the raw input x (GEMM epilogues fuse the split).
// ---------------------------------------------------------------------------
__global__ __launch_bounds__(256) void asplit(const float* __restrict__ in,
                                              ushort* __restrict__ o) {
  const int i4 = (blockIdx.x * 256 + threadIdx.x) * 4;
  const float4 v = *(const float4*)&in[i4];
  const int row = i4 >> 10, col = i4 & 1023;
  ushort h0 = f2bf(v.x), h1 = f2bf(v.y), h2 = f2bf(v.z), h3 = f2bf(v.w);
  ushort l0 = f2bf(v.x - bf2f(h0)), l1 = f2bf(v.y - bf2f(h1));
  ushort l2 = f2bf(v.z - bf2f(h2)), l3 = f2bf(v.w - bf2f(h3));
  uint2 hp, lp;
  hp.x = (uint)h0 | ((uint)h1 << 16); hp.y = (uint)h2 | ((uint)h3 << 16);
  lp.x = (uint)l0 | ((uint)l1 << 16); lp.y = (uint)l2 | ((uint)l3 << 16);
  *(uint2*)&o[(size_t)row * 2048 + col] = hp;
  *(uint2*)&o[(size_t)row * 2048 + 1024 + col] = lp;
}

// ---------------------------------------------------------------------------
// Weight split + transpose: W (1024,1024) [k][n] -> Wt (1024,2048) [n][k hi|lo]
// ---------------------------------------------------------------------------
__global__ __launch_bounds__(256) void wsplit_t(const float* __restrict__ W,
                                                ushort* __restrict__ Wt) {
  __shared__ float tile[32][33];
  const int bx = blockIdx.x, by = blockIdx.y;
  const int tx = threadIdx.x, ty = threadIdx.y;
#pragma unroll
  for (int r = ty; r < 32; r += 8)
    tile[r][tx] = W[(size_t)(by * 32 + r) * 1024 + bx * 32 + tx];
  __syncthreads();
#pragma unroll
  for (int r = ty; r < 32; r += 8) {
    const float v = tile[tx][r];  // = W[by*32+tx][bx*32+r]
    const ushort hi = f2bf(v);
    const ushort lo = f2bf(v - bf2f(hi));
    const size_t n = bx * 32 + r, k = by * 32 + tx;
    Wt[n * 2048 + k] = hi;
    Wt[n * 2048 + 1024 + k] = lo;
  }
}

// ---------------------------------------------------------------------------
// Encoder head: logits = h2 @ enc_w3 + b3 -> log-softmax (4 classes).
// h2 arrives as hi|lo bf16 (4096,2048); hv = hi+lo (2^-18 rel of fp32).
// ---------------------------------------------------------------------------
__global__ __launch_bounds__(256) void enc_head(
    const ushort* __restrict__ h2hl, const float* __restrict__ w3,
    const float* __restrict__ b3, float* __restrict__ logp) {
  const int wave = threadIdx.x >> 6;
  const int lane = threadIdx.x & 63;
  const int row = blockIdx.x * 4 + wave;
  const ushort* h = h2hl + (size_t)row * 2048;
  float a0 = 0.f, a1 = 0.f, a2 = 0.f, a3 = 0.f;
#pragma unroll
  for (int it = 0; it < 4; ++it) {
    const int k = it * 256 + lane * 4;
    const uint2 hp = *(const uint2*)&h[k];
    const uint2 lp = *(const uint2*)&h[1024 + k];
    float hv[4];
    hv[0] = bf2f((ushort)(hp.x & 0xffff)) + bf2f((ushort)(lp.x & 0xffff));
    hv[1] = bf2f((ushort)(hp.x >> 16)) + bf2f((ushort)(lp.x >> 16));
    hv[2] = bf2f((ushort)(hp.y & 0xffff)) + bf2f((ushort)(lp.y & 0xffff));
    hv[3] = bf2f((ushort)(hp.y >> 16)) + bf2f((ushort)(lp.y >> 16));
#pragma unroll
    for (int jj = 0; jj < 4; ++jj) {
      const float4 w = *(const float4*)&w3[(k + jj) * 4];
      a0 = fmaf(hv[jj], w.x, a0);
      a1 = fmaf(hv[jj], w.y, a1);
      a2 = fmaf(hv[jj], w.z, a2);
      a3 = fmaf(hv[jj], w.w, a3);
    }
  }
#pragma unroll
  for (int o = 32; o; o >>= 1) {
    a0 += __shfl_down(a0, o);
    a1 += __shfl_down(a1, o);
    a2 += __shfl_down(a2, o);
    a3 += __shfl_down(a3, o);
  }
  if (lane == 0) {
    const float l0 = a0 + b3[0], l1 = a1 + b3[1], l2 = a2 + b3[2], l3 = a3 + b3[3];
    const float m = fmaxf(fmaxf(l0, l1), fmaxf(l2, l3));
    const float e0 = expf(l0 - m), e1 = expf(l1 - m), e2 = expf(l2 - m), e3 = expf(l3 - m);
    const float ls = logf(e0 + e1 + e2 + e3);
    float4 lp;
    lp.x = l0 - m - ls;
    lp.y = l1 - m - ls;
    lp.z = l2 - m - ls;
    lp.w = l3 - m - ls;
    *(float4*)&logp[row * 4] = lp;
  }
}

__global__ void log_coeffs(const float* __restrict__ coeffs, float* __restrict__ lc) {
  const int v = blockIdx.x * 256 + threadIdx.x;
  if (v < VV) lc[v] = logf(coeffs[v]);
}

// ---------------------------------------------------------------------------
// Gumbel-softmax over count vectors -> mean_z. One block (256 thr) per row.
// ---------------------------------------------------------------------------
__global__ __launch_bounds__(256) void middle(
    const float* __restrict__ logp, const float* __restrict__ rand_grid,
    const float* __restrict__ cv4, const float* __restrict__ lcoef,
    float* __restrict__ mz) {
  __shared__ float s_s[VV];
  __shared__ float sred[4];
  __shared__ float rs[4][5];

  const int b = blockIdx.x;
  const int tid = threadIdx.x;
  const float4 lp = *(const float4*)&logp[b * 4];
  const float* u = rand_grid + (size_t)b * VV;

  float lmax = -INFINITY;
  for (int v = tid; v < VV; v += 256) {
    const float4 c = *(const float4*)&cv4[v * 4];
    float l = lcoef[v] + c.x * lp.x + c.y * lp.y + c.z * lp.z + c.w * lp.w;
    l = fminf(fmaxf(l, LOG_TINY), 0.0f);
    const float g = -logf(-logf(u[v]));
    const float sv = (l + g) * TAU_INV;
    s_s[v] = sv;
    lmax = fmaxf(lmax, sv);
  }
#pragma unroll
  for (int o = 32; o; o >>= 1) lmax = fmaxf(lmax, __shfl_down(lmax, o));
  if ((tid & 63) == 0) sred[tid >> 6] = lmax;
  __syncthreads();
  const float M = fmaxf(fmaxf(sred[0], sred[1]), fmaxf(sred[2], sred[3]));

  float sum = 0.f, w0 = 0.f, w1 = 0.f, w2 = 0.f, w3 = 0.f;
  for (int v = tid; v < VV; v += 256) {
    const float e = expf(s_s[v] - M);
    const float4 c = *(const float4*)&cv4[v * 4];
    sum += e;
    w0 = fmaf(e, c.x, w0);
    w1 = fmaf(e, c.y, w1);
    w2 = fmaf(e, c.z, w2);
    w3 = fmaf(e, c.w, w3);
  }
#pragma unroll
  for (int o = 32; o; o >>= 1) {
    sum += __shfl_down(sum, o);
    w0 += __shfl_down(w0, o);
    w1 += __shfl_down(w1, o);
    w2 += __shfl_down(w2, o);
    w3 += __shfl_down(w3, o);
  }
  if ((tid & 63) == 0) {
    const int w = tid >> 6;
    rs[w][0] = sum; rs[w][1] = w0; rs[w][2] = w1; rs[w][3] = w2; rs[w][4] = w3;
  }
  __syncthreads();
  if (tid == 0) {
    const float S = rs[0][0] + rs[1][0] + rs[2][0] + rs[3][0];
    const float inv = 1.0f / (S * (float)NTRIAL);
    float4 o;
    o.x = (rs[0][1] + rs[1][1] + rs[2][1] + rs[3][1]) * inv;
    o.y = (rs[0][2] + rs[1][2] + rs[2][2] + rs[3][2]) * inv;
    o.z = (rs[0][3] + rs[1][3] + rs[2][3] + rs[3][3]) * inv;
    o.w = (rs[0][4] + rs[1][4] + rs[2][4] + rs[3][4]) * inv;
    *(float4*)&mz[b * 4] = o;
  }
}

// ---------------------------------------------------------------------------
// Decoder layer 1: h3 = relu(mz @ dec_w1 + b1); (B,4)x(4,H) -> hi/lo bf16.
// ---------------------------------------------------------------------------
__global__ __launch_bounds__(256) void dec1(
    const float* __restrict__ mz, const float* __restrict__ w1,
    const float* __restrict__ b1, ushort* __restrict__ h3hl) {
  const int b = blockIdx.x;
  const int j = threadIdx.x << 2;
  const float4 m = *(const float4*)&mz[b * 4];
  float4 acc = *(const float4*)&b1[j];
  const float4 q0 = *(const float4*)&w1[j];
  const float4 q1 = *(const float4*)&w1[HH + j];
  const float4 q2 = *(const float4*)&w1[2 * HH + j];
  const float4 q3 = *(const float4*)&w1[3 * HH + j];
  acc.x = fmaf(m.x, q0.x, fmaf(m.y, q1.x, fmaf(m.z, q2.x, fmaf(m.w, q3.x, acc.x))));
  acc.y = fmaf(m.x, q0.y, fmaf(m.y, q1.y, fmaf(m.z, q2.y, fmaf(m.w, q3.y, acc.y))));
  acc.z = fmaf(m.x, q0.z, fmaf(m.y, q1.z, fmaf(m.z, q2.z, fmaf(m.w, q3.z, acc.z))));
  acc.w = fmaf(m.x, q0.w, fmaf(m.y, q1.w, fmaf(m.z, q2.w, fmaf(m.w, q3.w, acc.w))));
  acc.x = fmaxf(acc.x, 0.f);
  acc.y = fmaxf(acc.y, 0.f);
  acc.z = fmaxf(acc.z, 0.f);
  acc.w = fmaxf(acc.w, 0.f);
  const ushort h0 = f2bf(acc.x), h1 = f2bf(acc.y), h2 = f2bf(acc.z), h3 = f2bf(acc.w);
  const ushort l0 = f2bf(acc.x - bf2f(h0)), l1 = f2bf(acc.y - bf2f(h1));
  const ushort l2 = f2bf(acc.z - bf2f(h2)), l3 = f2bf(acc.w - bf2f(h3));
  uint2 hp, lp;
  hp.x = (uint)h0 | ((uint)h1 << 16); hp.y = (uint)h2 | ((uint)h3 << 16);
  lp.x = (uint)l0 | ((uint)l1 << 16); lp.y = (uint)l2 | ((uint)l3 << 16);
  *(uint2*)&h3hl[(size_t)b * 2048 + j] = hp;
  *(uint2*)&h3hl[(size_t)b * 2048 + 1024 + j] = lp;
}

// ---------------------------------------------------------------------------
// ws layout (36.2 MB): H1hl 16MB | H2hl 16MB | Wt 4MB (reused per GEMM) |
// logp/mz/lcoef small.  Xhl (16 MB) lives in d_out (consumed by GEMM1;
// final GEMM rewrites d_out).
// ---------------------------------------------------------------------------
extern "C" void kernel_launch(void* const* d_in, const int* in_sizes, int n_in,
                              void* d_out, int out_size, void* d_ws, size_t ws_size,
                              hipStream_t stream) {
  const float* x      = (const float*)d_in[0];
  const float* rand_g = (const float*)d_in[1];
  const float* enc_w1 = (const float*)d_in[2];
  const float* enc_b1 = (const float*)d_in[3];
  const float* enc_w2 = (const float*)d_in[4];
  const float* enc_b2 = (const float*)d_in[5];
  const float* enc_w3 = (const float*)d_in[6];
  const float* enc_b3 = (const float*)d_in[7];
  const float* dec_w1 = (const float*)d_in[8];
  const float* dec_b1 = (const float*)d_in[9];
  const float* dec_w2 = (const float*)d_in[10];
  const float* dec_b2 = (const float*)d_in[11];
  const float* dec_w3 = (const float*)d_in[12];
  const float* dec_b3 = (const float*)d_in[13];
  const float* cv4    = (const float*)d_in[14];
  const float* coeffs = (const float*)d_in[15];
  float* out = (float*)d_out;

  ushort* Xhl   = (ushort*)d_out;                      // 4096x2048 = 16 MB exact
  ushort* H1hl  = (ushort*)d_ws;                       // 16 MB
  ushort* H2hl  = H1hl + (size_t)BB * 2048;            // 16 MB
  ushort* Wt    = H2hl + (size_t)BB * 2048;            // 4 MB, reused per GEMM
  float*  logp  = (float*)(Wt + (size_t)1024 * 2048);
  float*  mzp   = logp + BB * 4;
  float*  lcoef = mzp + BB * 4;

  const dim3 mg(1024 / 128, BB / 128);  // (8, 32) = 256 wgs, 1/CU
  const dim3 wt_grid(32, 32), wt_blk(32, 8);

  log_coeffs<<<(VV + 255) / 256, 256, 0, stream>>>(coeffs, lcoef);
  asplit<<<(BB * DD) / 1024, 256, 0, stream>>>(x, Xhl);

  // encoder
  wsplit_t<<<wt_grid, wt_blk, 0, stream>>>(enc_w1, Wt);
  mfma_gemm<true, true><<<mg, 256, 0, stream>>>(Xhl, Wt, enc_b1, H1hl);
  wsplit_t<<<wt_grid, wt_blk, 0, stream>>>(enc_w2, Wt);
  mfma_gemm<true, true><<<mg, 256, 0, stream>>>(H1hl, Wt, enc_b2, H2hl);
  enc_head<<<BB / 4, 256, 0, stream>>>(H2hl, enc_w3, enc_b3, logp);

  // gumbel-softmax over count vectors
  middle<<<BB, 256, 0, stream>>>(logp, rand_g, cv4, lcoef, mzp);

  // decoder (H1hl reused for h3, H2hl for h4)
  dec1<<<BB, 256, 0, stream>>>(mzp, dec_w1, dec_b1, H1hl);
  wsplit_t<<<wt_grid, wt_blk, 0, stream>>>(dec_w2, Wt);
  mfma_gemm<true, true><<<mg, 256, 0, stream>>>(H1hl, Wt, dec_b2, H2hl);
  wsplit_t<<<wt_grid, wt_blk, 0, stream>>>(dec_w3, Wt);
  mfma_gemm<false, false><<<mg, 256, 0, stream>>>(H2hl, Wt, dec_b3, out);
}

// Round 12
// 355.806 us; speedup vs baseline: 8.2124x; 1.2793x over previous
//
#include <hip/hip_runtime.h>
#include <hip/hip_bf16.h>
#include <cstdint>

// Problem constants (Multinomial VAE)
#define BB 4096
#define DD 1024
#define HH 1024
#define NTRIAL 24
#define VV 2925
#define TAU_INV 100.0f
#define LOG_TINY -87.336544750402f  // logf(1.17549435e-38f)

typedef unsigned int uint;
typedef unsigned short ushort;
typedef __attribute__((ext_vector_type(8))) short short8v;  // 8 bf16 (4 VGPRs)
typedef __attribute__((ext_vector_type(4))) float f32x4;

// bf16 helpers (RNE)
__device__ __forceinline__ ushort f2bf(float f) {
  uint u = __float_as_uint(f);
  uint r = u + 0x7fffu + ((u >> 16) & 1u);
  return (ushort)(r >> 16);
}
__device__ __forceinline__ float bf2f(ushort h) {
  return __uint_as_float(((uint)h) << 16);
}

// async global->LDS, 16B per lane; LDS dest must be wave-uniform base
// (HW writes base + lane*16), global src is per-lane.
typedef const __attribute__((address_space(1))) uint g_u32;
typedef __attribute__((address_space(3))) uint l_u32;
__device__ __forceinline__ void gl_lds16(const ushort* g, ushort* l) {
  __builtin_amdgcn_global_load_lds((g_u32*)g, (l_u32*)l, 16, 0, 0);
}

// ---------------------------------------------------------------------------
// MFMA bf16x2-split GEMM, FUSED 3-product K-loop:
//   acc += Ahi*Whi + Alo*Whi + Ahi*Wlo   (lo*lo dropped, ~2^-18 rel)
// per k-step all four tiles (Ahi,Alo,Whi,Wlo) are staged once -> 32 kt
// (was 96 with 3 sequential product passes) => 3x fewer barrier drains,
// A-hi/W-hi staged once instead of twice.
// Tile 128x64, 512 wgs = 2 blocks/CU (was 256 = 1/CU: vmcnt(0) drain at
// each __syncthreads was fully exposed, Occupancy 10%, 95% stall).
// LDS 48 KB double-buffered; global_load_lds staging; XOR swizzle
// slot^=(row>>1)&3 on global source + ds_read (HW-verified: 0 conflicts).
// XCD-aware bijective swizzle (512%8==0): each XCD owns 4 m-panels x all
// n-tiles -> per-kt working set ~192 KB, L2-resident.
// ---------------------------------------------------------------------------
template <bool RELU, bool OUT_HL>
__global__ __launch_bounds__(256, 2) void mfma_gemm(
    const ushort* __restrict__ Ahl, const ushort* __restrict__ Wt,
    const float* __restrict__ bias, void* __restrict__ Cout) {
  __shared__ ushort Ah[2][128 * 32];
  __shared__ ushort Al[2][128 * 32];
  __shared__ ushort Wh[2][64 * 32];
  __shared__ ushort Wl[2][64 * 32];

  const int bid = blockIdx.x;
  const int swz = (bid & 7) * 64 + (bid >> 3);  // XCD-contiguous mapping
  const int m0 = (swz >> 4) * 128;              // 32 m-tiles
  const int n0 = (swz & 15) * 64;               // 16 n-tiles

  const int t = threadIdx.x;
  const int wv = t >> 6, lane = t & 63;
  const int wr = wv >> 1, wc = wv & 1;          // wave tile: rows wr*64, cols wc*32
  const int lrow = lane & 15, lk = lane >> 4;   // frag row/col + K-chunk

  const int sub = lane >> 2;   // 0..15 row within a 16-row DMA segment
  const int slot = lane & 3;   // 16B slot within the 64B LDS row

  f32x4 acc[4][2] = {};

  auto STAGE = [&](int b, int kt) {
    const int k0 = kt * 32;
#pragma unroll
    for (int c = 0; c < 2; ++c) {               // A rows [wv*32, wv*32+32)
      const int row = wv * 32 + c * 16 + sub;
      const int sc = slot ^ ((row >> 1) & 3);   // inverse-swizzled source chunk
      const ushort* gA = Ahl + (size_t)(m0 + row) * 2048 + k0 + sc * 8;
      gl_lds16(gA, &Ah[b][(wv * 32 + c * 16) * 32]);
      gl_lds16(gA + 1024, &Al[b][(wv * 32 + c * 16) * 32]);
    }
    {                                           // W rows [wv*16, wv*16+16)
      const int row = wv * 16 + sub;
      const int sc = slot ^ ((row >> 1) & 3);
      const ushort* gW = Wt + (size_t)(n0 + row) * 2048 + k0 + sc * 8;
      gl_lds16(gW, &Wh[b][(wv * 16) * 32]);
      gl_lds16(gW + 1024, &Wl[b][(wv * 16) * 32]);
    }
  };

  STAGE(0, 0);
  __syncthreads();
  int cur = 0;
#pragma unroll 2
  for (int kt = 0; kt < 32; ++kt) {
    if (kt + 1 < 32) STAGE(cur ^ 1, kt + 1);
    const ushort* ah = Ah[cur];
    const ushort* al_ = Al[cur];
    const ushort* wh = Wh[cur];
    const ushort* wl = Wl[cur];
    short8v af[4], av[4], bh[2], bl[2];
#pragma unroll
    for (int i = 0; i < 4; ++i) {
      const int row = wr * 64 + i * 16 + lrow;
      const int off = row * 32 + (lk ^ ((row >> 1) & 3)) * 8;
      af[i] = *(const short8v*)&ah[off];
      av[i] = *(const short8v*)&al_[off];
    }
#pragma unroll
    for (int j = 0; j < 2; ++j) {
      const int row = wc * 32 + j * 16 + lrow;
      const int off = row * 32 + (lk ^ ((row >> 1) & 3)) * 8;
      bh[j] = *(const short8v*)&wh[off];
      bl[j] = *(const short8v*)&wl[off];
    }
#pragma unroll
    for (int i = 0; i < 4; ++i)
#pragma unroll
      for (int j = 0; j < 2; ++j) {
        acc[i][j] = __builtin_amdgcn_mfma_f32_16x16x32_bf16(af[i], bh[j], acc[i][j], 0, 0, 0);
        acc[i][j] = __builtin_amdgcn_mfma_f32_16x16x32_bf16(av[i], bh[j], acc[i][j], 0, 0, 0);
        acc[i][j] = __builtin_amdgcn_mfma_f32_16x16x32_bf16(af[i], bl[j], acc[i][j], 0, 0, 0);
      }
    __syncthreads();   // drains lgkmcnt (reads done) and vmcnt (DMA done)
    cur ^= 1;
  }

  // epilogue: D col = lane&15, row = (lane>>4)*4 + q (m89-verified layout)
  ushort* Chl = (ushort*)Cout;
  float* Cf = (float*)Cout;
#pragma unroll
  for (int j = 0; j < 2; ++j) {
    const int c = n0 + wc * 32 + j * 16 + lrow;
    const float bv = bias[c];
#pragma unroll
    for (int i = 0; i < 4; ++i) {
#pragma unroll
      for (int q = 0; q < 4; ++q) {
        const int r = m0 + wr * 64 + i * 16 + lk * 4 + q;
        float v = acc[i][j][q] + bv;
        if (RELU) v = fmaxf(v, 0.f);
        if (OUT_HL) {
          const ushort hi = f2bf(v);
          const ushort lo = f2bf(v - bf2f(hi));
          Chl[(size_t)r * 2048 + c] = hi;
          Chl[(size_t)r * 2048 + 1024 + c] = lo;
        } else {
          Cf[(size_t)r * 1024 + c] = v;
        }
      }
    }
  }
}

// ---------------------------------------------------------------------------
// Activation split: fp32 (4096,1024) -> bf16 hi/lo packed (4096,2048).
// Only needed for the raw input x (GEMM epilogues fuse the split).
// ---------------------------------------------------------------------------
__global__ __launch_bounds__(256) void asplit(const float* __restrict__ in,
                                              ushort* __restrict__ o) {
  const int i4 = (blockIdx.x * 256 + threadIdx.x) * 4;
  const float4 v = *(const float4*)&in[i4];
  const int row = i4 >> 10, col = i4 & 1023;
  ushort h0 = f2bf(v.x), h1 = f2bf(v.y), h2 = f2bf(v.z), h3 = f2bf(v.w);
  ushort l0 = f2bf(v.x - bf2f(h0)), l1 = f2bf(v.y - bf2f(h1));
  ushort l2 = f2bf(v.z - bf2f(h2)), l3 = f2bf(v.w - bf2f(h3));
  uint2 hp, lp;
  hp.x = (uint)h0 | ((uint)h1 << 16); hp.y = (uint)h2 | ((uint)h3 << 16);
  lp.x = (uint)l0 | ((uint)l1 << 16); lp.y = (uint)l2 | ((uint)l3 << 16);
  *(uint2*)&o[(size_t)row * 2048 + col] = hp;
  *(uint2*)&o[(size_t)row * 2048 + 1024 + col] = lp;
}

// ---------------------------------------------------------------------------
// Weight split + transpose: W (1024,1024) [k][n] -> Wt (1024,2048) [n][k hi|lo]
// ---------------------------------------------------------------------------
__global__ __launch_bounds__(256) void wsplit_t(const float* __restrict__ W,
                                                ushort* __restrict__ Wt) {
  __shared__ float tile[32][33];
  const int bx = blockIdx.x, by = blockIdx.y;
  const int tx = threadIdx.x, ty = threadIdx.y;
#pragma unroll
  for (int r = ty; r < 32; r += 8)
    tile[r][tx] = W[(size_t)(by * 32 + r) * 1024 + bx * 32 + tx];
  __syncthreads();
#pragma unroll
  for (int r = ty; r < 32; r += 8) {
    const float v = tile[tx][r];  // = W[by*32+tx][bx*32+r]
    const ushort hi = f2bf(v);
    const ushort lo = f2bf(v - bf2f(hi));
    const size_t n = bx * 32 + r, k = by * 32 + tx;
    Wt[n * 2048 + k] = hi;
    Wt[n * 2048 + 1024 + k] = lo;
  }
}

// ---------------------------------------------------------------------------
// Encoder head: logits = h2 @ enc_w3 + b3 -> log-softmax (4 classes).
// h2 arrives as hi|lo bf16 (4096,2048); hv = hi+lo (2^-18 rel of fp32).
// ---------------------------------------------------------------------------
__global__ __launch_bounds__(256) void enc_head(
    const ushort* __restrict__ h2hl, const float* __restrict__ w3,
    const float* __restrict__ b3, float* __restrict__ logp) {
  const int wave = threadIdx.x >> 6;
  const int lane = threadIdx.x & 63;
  const int row = blockIdx.x * 4 + wave;
  const ushort* h = h2hl + (size_t)row * 2048;
  float a0 = 0.f, a1 = 0.f, a2 = 0.f, a3 = 0.f;
#pragma unroll
  for (int it = 0; it < 4; ++it) {
    const int k = it * 256 + lane * 4;
    const uint2 hp = *(const uint2*)&h[k];
    const uint2 lp = *(const uint2*)&h[1024 + k];
    float hv[4];
    hv[0] = bf2f((ushort)(hp.x & 0xffff)) + bf2f((ushort)(lp.x & 0xffff));
    hv[1] = bf2f((ushort)(hp.x >> 16)) + bf2f((ushort)(lp.x >> 16));
    hv[2] = bf2f((ushort)(hp.y & 0xffff)) + bf2f((ushort)(lp.y & 0xffff));
    hv[3] = bf2f((ushort)(hp.y >> 16)) + bf2f((ushort)(lp.y >> 16));
#pragma unroll
    for (int jj = 0; jj < 4; ++jj) {
      const float4 w = *(const float4*)&w3[(k + jj) * 4];
      a0 = fmaf(hv[jj], w.x, a0);
      a1 = fmaf(hv[jj], w.y, a1);
      a2 = fmaf(hv[jj], w.z, a2);
      a3 = fmaf(hv[jj], w.w, a3);
    }
  }
#pragma unroll
  for (int o = 32; o; o >>= 1) {
    a0 += __shfl_down(a0, o);
    a1 += __shfl_down(a1, o);
    a2 += __shfl_down(a2, o);
    a3 += __shfl_down(a3, o);
  }
  if (lane == 0) {
    const float l0 = a0 + b3[0], l1 = a1 + b3[1], l2 = a2 + b3[2], l3 = a3 + b3[3];
    const float m = fmaxf(fmaxf(l0, l1), fmaxf(l2, l3));
    const float e0 = expf(l0 - m), e1 = expf(l1 - m), e2 = expf(l2 - m), e3 = expf(l3 - m);
    const float ls = logf(e0 + e1 + e2 + e3);
    float4 lp;
    lp.x = l0 - m - ls;
    lp.y = l1 - m - ls;
    lp.z = l2 - m - ls;
    lp.w = l3 - m - ls;
    *(float4*)&logp[row * 4] = lp;
  }
}

__global__ void log_coeffs(const float* __restrict__ coeffs, float* __restrict__ lc) {
  const int v = blockIdx.x * 256 + threadIdx.x;
  if (v < VV) lc[v] = logf(coeffs[v]);
}

// ---------------------------------------------------------------------------
// Gumbel-softmax over count vectors -> mean_z. One block (256 thr) per row.
// ---------------------------------------------------------------------------
__global__ __launch_bounds__(256) void middle(
    const float* __restrict__ logp, const float* __restrict__ rand_grid,
    const float* __restrict__ cv4, const float* __restrict__ lcoef,
    float* __restrict__ mz) {
  __shared__ float s_s[VV];
  __shared__ float sred[4];
  __shared__ float rs[4][5];

  const int b = blockIdx.x;
  const int tid = threadIdx.x;
  const float4 lp = *(const float4*)&logp[b * 4];
  const float* u = rand_grid + (size_t)b * VV;

  float lmax = -INFINITY;
  for (int v = tid; v < VV; v += 256) {
    const float4 c = *(const float4*)&cv4[v * 4];
    float l = lcoef[v] + c.x * lp.x + c.y * lp.y + c.z * lp.z + c.w * lp.w;
    l = fminf(fmaxf(l, LOG_TINY), 0.0f);
    const float g = -logf(-logf(u[v]));
    const float sv = (l + g) * TAU_INV;
    s_s[v] = sv;
    lmax = fmaxf(lmax, sv);
  }
#pragma unroll
  for (int o = 32; o; o >>= 1) lmax = fmaxf(lmax, __shfl_down(lmax, o));
  if ((tid & 63) == 0) sred[tid >> 6] = lmax;
  __syncthreads();
  const float M = fmaxf(fmaxf(sred[0], sred[1]), fmaxf(sred[2], sred[3]));

  float sum = 0.f, w0 = 0.f, w1 = 0.f, w2 = 0.f, w3 = 0.f;
  for (int v = tid; v < VV; v += 256) {
    const float e = expf(s_s[v] - M);
    const float4 c = *(const float4*)&cv4[v * 4];
    sum += e;
    w0 = fmaf(e, c.x, w0);
    w1 = fmaf(e, c.y, w1);
    w2 = fmaf(e, c.z, w2);
    w3 = fmaf(e, c.w, w3);
  }
#pragma unroll
  for (int o = 32; o; o >>= 1) {
    sum += __shfl_down(sum, o);
    w0 += __shfl_down(w0, o);
    w1 += __shfl_down(w1, o);
    w2 += __shfl_down(w2, o);
    w3 += __shfl_down(w3, o);
  }
  if ((tid & 63) == 0) {
    const int w = tid >> 6;
    rs[w][0] = sum; rs[w][1] = w0; rs[w][2] = w1; rs[w][3] = w2; rs[w][4] = w3;
  }
  __syncthreads();
  if (tid == 0) {
    const float S = rs[0][0] + rs[1][0] + rs[2][0] + rs[3][0];
    const float inv = 1.0f / (S * (float)NTRIAL);
    float4 o;
    o.x = (rs[0][1] + rs[1][1] + rs[2][1] + rs[3][1]) * inv;
    o.y = (rs[0][2] + rs[1][2] + rs[2][2] + rs[3][2]) * inv;
    o.z = (rs[0][3] + rs[1][3] + rs[2][3] + rs[3][3]) * inv;
    o.w = (rs[0][4] + rs[1][4] + rs[2][4] + rs[3][4]) * inv;
    *(float4*)&mz[b * 4] = o;
  }
}

// ---------------------------------------------------------------------------
// Decoder layer 1: h3 = relu(mz @ dec_w1 + b1); (B,4)x(4,H) -> hi/lo bf16.
// ---------------------------------------------------------------------------
__global__ __launch_bounds__(256) void dec1(
    const float* __restrict__ mz, const float* __restrict__ w1,
    const float* __restrict__ b1, ushort* __restrict__ h3hl) {
  const int b = blockIdx.x;
  const int j = threadIdx.x << 2;
  const float4 m = *(const float4*)&mz[b * 4];
  float4 acc = *(const float4*)&b1[j];
  const float4 q0 = *(const float4*)&w1[j];
  const float4 q1 = *(const float4*)&w1[HH + j];
  const float4 q2 = *(const float4*)&w1[2 * HH + j];
  const float4 q3 = *(const float4*)&w1[3 * HH + j];
  acc.x = fmaf(m.x, q0.x, fmaf(m.y, q1.x, fmaf(m.z, q2.x, fmaf(m.w, q3.x, acc.x))));
  acc.y = fmaf(m.x, q0.y, fmaf(m.y, q1.y, fmaf(m.z, q2.y, fmaf(m.w, q3.y, acc.y))));
  acc.z = fmaf(m.x, q0.z, fmaf(m.y, q1.z, fmaf(m.z, q2.z, fmaf(m.w, q3.z, acc.z))));
  acc.w = fmaf(m.x, q0.w, fmaf(m.y, q1.w, fmaf(m.z, q2.w, fmaf(m.w, q3.w, acc.w))));
  acc.x = fmaxf(acc.x, 0.f);
  acc.y = fmaxf(acc.y, 0.f);
  acc.z = fmaxf(acc.z, 0.f);
  acc.w = fmaxf(acc.w, 0.f);
  const ushort h0 = f2bf(acc.x), h1 = f2bf(acc.y), h2 = f2bf(acc.z), h3 = f2bf(acc.w);
  const ushort l0 = f2bf(acc.x - bf2f(h0)), l1 = f2bf(acc.y - bf2f(h1));
  const ushort l2 = f2bf(acc.z - bf2f(h2)), l3 = f2bf(acc.w - bf2f(h3));
  uint2 hp, lp;
  hp.x = (uint)h0 | ((uint)h1 << 16); hp.y = (uint)h2 | ((uint)h3 << 16);
  lp.x = (uint)l0 | ((uint)l1 << 16); lp.y = (uint)l2 | ((uint)l3 << 16);
  *(uint2*)&h3hl[(size_t)b * 2048 + j] = hp;
  *(uint2*)&h3hl[(size_t)b * 2048 + 1024 + j] = lp;
}

// ---------------------------------------------------------------------------
// ws layout (36.2 MB): H1hl 16MB | H2hl 16MB | Wt 4MB (reused per GEMM) |
// logp/mz/lcoef small.  Xhl (16 MB) lives in d_out (consumed by GEMM1;
// final GEMM rewrites d_out).
// ---------------------------------------------------------------------------
extern "C" void kernel_launch(void* const* d_in, const int* in_sizes, int n_in,
                              void* d_out, int out_size, void* d_ws, size_t ws_size,
                              hipStream_t stream) {
  const float* x      = (const float*)d_in[0];
  const float* rand_g = (const float*)d_in[1];
  const float* enc_w1 = (const float*)d_in[2];
  const float* enc_b1 = (const float*)d_in[3];
  const float* enc_w2 = (const float*)d_in[4];
  const float* enc_b2 = (const float*)d_in[5];
  const float* enc_w3 = (const float*)d_in[6];
  const float* enc_b3 = (const float*)d_in[7];
  const float* dec_w1 = (const float*)d_in[8];
  const float* dec_b1 = (const float*)d_in[9];
  const float* dec_w2 = (const float*)d_in[10];
  const float* dec_b2 = (const float*)d_in[11];
  const float* dec_w3 = (const float*)d_in[12];
  const float* dec_b3 = (const float*)d_in[13];
  const float* cv4    = (const float*)d_in[14];
  const float* coeffs = (const float*)d_in[15];
  float* out = (float*)d_out;

  ushort* Xhl   = (ushort*)d_out;                      // 4096x2048 = 16 MB exact
  ushort* H1hl  = (ushort*)d_ws;                       // 16 MB
  ushort* H2hl  = H1hl + (size_t)BB * 2048;            // 16 MB
  ushort* Wt    = H2hl + (size_t)BB * 2048;            // 4 MB, reused per GEMM
  float*  logp  = (float*)(Wt + (size_t)1024 * 2048);
  float*  mzp   = logp + BB * 4;
  float*  lcoef = mzp + BB * 4;

  const int mg = 512;                  // (32 m-tiles x 16 n-tiles), XCD-swizzled
  const dim3 wt_grid(32, 32), wt_blk(32, 8);

  log_coeffs<<<(VV + 255) / 256, 256, 0, stream>>>(coeffs, lcoef);
  asplit<<<(BB * DD) / 1024, 256, 0, stream>>>(x, Xhl);

  // encoder
  wsplit_t<<<wt_grid, wt_blk, 0, stream>>>(enc_w1, Wt);
  mfma_gemm<true, true><<<mg, 256, 0, stream>>>(Xhl, Wt, enc_b1, H1hl);
  wsplit_t<<<wt_grid, wt_blk, 0, stream>>>(enc_w2, Wt);
  mfma_gemm<true, true><<<mg, 256, 0, stream>>>(H1hl, Wt, enc_b2, H2hl);
  enc_head<<<BB / 4, 256, 0, stream>>>(H2hl, enc_w3, enc_b3, logp);

  // gumbel-softmax over count vectors
  middle<<<BB, 256, 0, stream>>>(logp, rand_g, cv4, lcoef, mzp);

  // decoder (H1hl reused for h3, H2hl for h4)
  dec1<<<BB, 256, 0, stream>>>(mzp, dec_w1, dec_b1, H1hl);
  wsplit_t<<<wt_grid, wt_blk, 0, stream>>>(dec_w2, Wt);
  mfma_gemm<true, true><<<mg, 256, 0, stream>>>(H1hl, Wt, dec_b2, H2hl);
  wsplit_t<<<wt_grid, wt_blk, 0, stream>>>(dec_w3, Wt);
  mfma_gemm<false, false><<<mg, 256, 0, stream>>>(H2hl, Wt, dec_b3, out);
}

// Round 13
// 339.803 us; speedup vs baseline: 8.5992x; 1.0471x over previous
//
#include <hip/hip_runtime.h>
#include <hip/hip_bf16.h>
#include <cstdint>

// Problem constants (Multinomial VAE)
#define BB 4096
#define DD 1024
#define HH 1024
#define NTRIAL 24
#define VV 2925
#define TAU_INV 100.0f
#define LOG_TINY -87.336544750402f  // logf(1.17549435e-38f)

typedef unsigned int uint;
typedef unsigned short ushort;
typedef __attribute__((ext_vector_type(8))) short short8v;  // 8 bf16 (4 VGPRs)
typedef __attribute__((ext_vector_type(4))) float f32x4;

// bf16 helpers (RNE)
__device__ __forceinline__ ushort f2bf(float f) {
  uint u = __float_as_uint(f);
  uint r = u + 0x7fffu + ((u >> 16) & 1u);
  return (ushort)(r >> 16);
}
__device__ __forceinline__ float bf2f(ushort h) {
  return __uint_as_float(((uint)h) << 16);
}

// async global->LDS, 16B per lane; LDS dest must be wave-uniform base
// (HW writes base + lane*16), global src is per-lane.
typedef const __attribute__((address_space(1))) uint g_u32;
typedef __attribute__((address_space(3))) uint l_u32;
__device__ __forceinline__ void gl_lds16(const ushort* g, ushort* l) {
  __builtin_amdgcn_global_load_lds((g_u32*)g, (l_u32*)l, 16, 0, 0);
}

#define VMCNT(n) asm volatile("s_waitcnt vmcnt(" #n ")" ::: "memory")

// ---------------------------------------------------------------------------
// MFMA bf16x2-split GEMM, FUSED 3-product K-loop + TRIPLE-BUFFERED DMA with
// counted vmcnt (T3/T4): round-12's __syncthreads drained vmcnt(0) per kt,
// exposing full DMA latency (3375 cyc/kt vs ~230 MFMA). Now iter j issues
// STAGE(j+2) into buf[(j+2)%3], reads buf[j%3], then waits vmcnt(6) (tile
// j+2's 6 ops stay in flight; in-order vmcnt retirement guarantees tile j+1
// complete) + sched_barrier + raw s_barrier. Never drains to 0 mid-loop.
// WAR safe: STAGE(j+2) overwrites buf[(j-1)%3] whose reads retired before
// barrier(j-1); write/read bufs differ by 2 mod 3.
//   acc += Ahi*Whi + Alo*Whi + Ahi*Wlo   (lo*lo dropped, ~2^-18 rel)
// Tile 128x64, 512 wgs = 2 blocks/CU (LDS 72 KB x2 = 144 <= 160).
// XOR swizzle slot^=(row>>1)&3 on global source + ds_read (HW: 0 conflicts).
// XCD-aware bijective grid swizzle (HW: FETCH 101 -> 24.6 MB).
// ---------------------------------------------------------------------------
template <bool RELU, bool OUT_HL>
__global__ __launch_bounds__(256, 2) void mfma_gemm(
    const ushort* __restrict__ Ahl, const ushort* __restrict__ Wt,
    const float* __restrict__ bias, void* __restrict__ Cout) {
  __shared__ ushort Ah[3][128 * 32];
  __shared__ ushort Al[3][128 * 32];
  __shared__ ushort Wh[3][64 * 32];
  __shared__ ushort Wl[3][64 * 32];

  const int bid = blockIdx.x;
  const int swz = (bid & 7) * 64 + (bid >> 3);  // XCD-contiguous mapping
  const int m0 = (swz >> 4) * 128;              // 32 m-tiles
  const int n0 = (swz & 15) * 64;               // 16 n-tiles

  const int t = threadIdx.x;
  const int wv = t >> 6, lane = t & 63;
  const int wr = wv >> 1, wc = wv & 1;          // wave tile: rows wr*64, cols wc*32
  const int lrow = lane & 15, lk = lane >> 4;   // frag row/col + K-chunk

  const int sub = lane >> 2;   // 0..15 row within a 16-row DMA segment
  const int slot = lane & 3;   // 16B slot within the 64B LDS row

  f32x4 acc[4][2] = {};

  // 6 gl_lds16 per thread per call (A:4, W:2)
  auto STAGE = [&](int b, int kt) {
    const int k0 = kt * 32;
#pragma unroll
    for (int c = 0; c < 2; ++c) {               // A rows [wv*32, wv*32+32)
      const int row = wv * 32 + c * 16 + sub;
      const int sc = slot ^ ((row >> 1) & 3);   // inverse-swizzled source chunk
      const ushort* gA = Ahl + (size_t)(m0 + row) * 2048 + k0 + sc * 8;
      gl_lds16(gA, &Ah[b][(wv * 32 + c * 16) * 32]);
      gl_lds16(gA + 1024, &Al[b][(wv * 32 + c * 16) * 32]);
    }
    {                                           // W rows [wv*16, wv*16+16)
      const int row = wv * 16 + sub;
      const int sc = slot ^ ((row >> 1) & 3);
      const ushort* gW = Wt + (size_t)(n0 + row) * 2048 + k0 + sc * 8;
      gl_lds16(gW, &Wh[b][(wv * 16) * 32]);
      gl_lds16(gW + 1024, &Wl[b][(wv * 16) * 32]);
    }
  };

  // prologue: tiles 0 and 1 in flight; wait for tile 0 only (vmcnt(6))
  STAGE(0, 0);
  STAGE(1, 1);
  VMCNT(6);
  __builtin_amdgcn_sched_barrier(0);
  __builtin_amdgcn_s_barrier();

#pragma unroll 1
  for (int kt = 0; kt < 32; ++kt) {
    if (kt + 2 < 32) STAGE((kt + 2) % 3, kt + 2);
    const int cb = kt % 3;
    const ushort* ah = Ah[cb];
    const ushort* al_ = Al[cb];
    const ushort* wh = Wh[cb];
    const ushort* wl = Wl[cb];
    short8v af[4], av[4], bh[2], bl[2];
#pragma unroll
    for (int i = 0; i < 4; ++i) {
      const int row = wr * 64 + i * 16 + lrow;
      const int off = row * 32 + (lk ^ ((row >> 1) & 3)) * 8;
      af[i] = *(const short8v*)&ah[off];
      av[i] = *(const short8v*)&al_[off];
    }
#pragma unroll
    for (int j = 0; j < 2; ++j) {
      const int row = wc * 32 + j * 16 + lrow;
      const int off = row * 32 + (lk ^ ((row >> 1) & 3)) * 8;
      bh[j] = *(const short8v*)&wh[off];
      bl[j] = *(const short8v*)&wl[off];
    }
#pragma unroll
    for (int i = 0; i < 4; ++i)
#pragma unroll
      for (int j = 0; j < 2; ++j) {
        acc[i][j] = __builtin_amdgcn_mfma_f32_16x16x32_bf16(af[i], bh[j], acc[i][j], 0, 0, 0);
        acc[i][j] = __builtin_amdgcn_mfma_f32_16x16x32_bf16(av[i], bh[j], acc[i][j], 0, 0, 0);
        acc[i][j] = __builtin_amdgcn_mfma_f32_16x16x32_bf16(af[i], bl[j], acc[i][j], 0, 0, 0);
      }
    // wait: tile kt+1 complete (all but the newest 6 ops = tile kt+2);
    // when no tile kt+2 was issued, drain remaining (epilogue iters).
    if (kt < 30) { VMCNT(6); } else { VMCNT(0); }
    __builtin_amdgcn_sched_barrier(0);
    __builtin_amdgcn_s_barrier();
  }

  // epilogue: D col = lane&15, row = (lane>>4)*4 + q (m89-verified layout)
  ushort* Chl = (ushort*)Cout;
  float* Cf = (float*)Cout;
#pragma unroll
  for (int j = 0; j < 2; ++j) {
    const int c = n0 + wc * 32 + j * 16 + lrow;
    const float bv = bias[c];
#pragma unroll
    for (int i = 0; i < 4; ++i) {
#pragma unroll
      for (int q = 0; q < 4; ++q) {
        const int r = m0 + wr * 64 + i * 16 + lk * 4 + q;
        float v = acc[i][j][q] + bv;
        if (RELU) v = fmaxf(v, 0.f);
        if (OUT_HL) {
          const ushort hi = f2bf(v);
          const ushort lo = f2bf(v - bf2f(hi));
          Chl[(size_t)r * 2048 + c] = hi;
          Chl[(size_t)r * 2048 + 1024 + c] = lo;
        } else {
          Cf[(size_t)r * 1024 + c] = v;
        }
      }
    }
  }
}

// ---------------------------------------------------------------------------
// Activation split: fp32 (4096,1024) -> bf16 hi/lo packed (4096,2048).
// Only needed for the raw input x (GEMM epilogues fuse the split).
// ---------------------------------------------------------------------------
__global__ __launch_bounds__(256) void asplit(const float* __restrict__ in,
                                              ushort* __restrict__ o) {
  const int i4 = (blockIdx.x * 256 + threadIdx.x) * 4;
  const float4 v = *(const float4*)&in[i4];
  const int row = i4 >> 10, col = i4 & 1023;
  ushort h0 = f2bf(v.x), h1 = f2bf(v.y), h2 = f2bf(v.z), h3 = f2bf(v.w);
  ushort l0 = f2bf(v.x - bf2f(h0)), l1 = f2bf(v.y - bf2f(h1));
  ushort l2 = f2bf(v.z - bf2f(h2)), l3 = f2bf(v.w - bf2f(h3));
  uint2 hp, lp;
  hp.x = (uint)h0 | ((uint)h1 << 16); hp.y = (uint)h2 | ((uint)h3 << 16);
  lp.x = (uint)l0 | ((uint)l1 << 16); lp.y = (uint)l2 | ((uint)l3 << 16);
  *(uint2*)&o[(size_t)row * 2048 + col] = hp;
  *(uint2*)&o[(size_t)row * 2048 + 1024 + col] = lp;
}

// ---------------------------------------------------------------------------
// Weight split + transpose: W (1024,1024) [k][n] -> Wt (1024,2048) [n][k hi|lo]
// ---------------------------------------------------------------------------
__global__ __launch_bounds__(256) void wsplit_t(const float* __restrict__ W,
                                                ushort* __restrict__ Wt) {
  __shared__ float tile[32][33];
  const int bx = blockIdx.x, by = blockIdx.y;
  const int tx = threadIdx.x, ty = threadIdx.y;
#pragma unroll
  for (int r = ty; r < 32; r += 8)
    tile[r][tx] = W[(size_t)(by * 32 + r) * 1024 + bx * 32 + tx];
  __syncthreads();
#pragma unroll
  for (int r = ty; r < 32; r += 8) {
    const float v = tile[tx][r];  // = W[by*32+tx][bx*32+r]
    const ushort hi = f2bf(v);
    const ushort lo = f2bf(v - bf2f(hi));
    const size_t n = bx * 32 + r, k = by * 32 + tx;
    Wt[n * 2048 + k] = hi;
    Wt[n * 2048 + 1024 + k] = lo;
  }
}

// ---------------------------------------------------------------------------
// Encoder head: logits = h2 @ enc_w3 + b3 -> log-softmax (4 classes).
// h2 arrives as hi|lo bf16 (4096,2048); hv = hi+lo (2^-18 rel of fp32).
// ---------------------------------------------------------------------------
__global__ __launch_bounds__(256) void enc_head(
    const ushort* __restrict__ h2hl, const float* __restrict__ w3,
    const float* __restrict__ b3, float* __restrict__ logp) {
  const int wave = threadIdx.x >> 6;
  const int lane = threadIdx.x & 63;
  const int row = blockIdx.x * 4 + wave;
  const ushort* h = h2hl + (size_t)row * 2048;
  float a0 = 0.f, a1 = 0.f, a2 = 0.f, a3 = 0.f;
#pragma unroll
  for (int it = 0; it < 4; ++it) {
    const int k = it * 256 + lane * 4;
    const uint2 hp = *(const uint2*)&h[k];
    const uint2 lp = *(const uint2*)&h[1024 + k];
    float hv[4];
    hv[0] = bf2f((ushort)(hp.x & 0xffff)) + bf2f((ushort)(lp.x & 0xffff));
    hv[1] = bf2f((ushort)(hp.x >> 16)) + bf2f((ushort)(lp.x >> 16));
    hv[2] = bf2f((ushort)(hp.y & 0xffff)) + bf2f((ushort)(lp.y & 0xffff));
    hv[3] = bf2f((ushort)(hp.y >> 16)) + bf2f((ushort)(lp.y >> 16));
#pragma unroll
    for (int jj = 0; jj < 4; ++jj) {
      const float4 w = *(const float4*)&w3[(k + jj) * 4];
      a0 = fmaf(hv[jj], w.x, a0);
      a1 = fmaf(hv[jj], w.y, a1);
      a2 = fmaf(hv[jj], w.z, a2);
      a3 = fmaf(hv[jj], w.w, a3);
    }
  }
#pragma unroll
  for (int o = 32; o; o >>= 1) {
    a0 += __shfl_down(a0, o);
    a1 += __shfl_down(a1, o);
    a2 += __shfl_down(a2, o);
    a3 += __shfl_down(a3, o);
  }
  if (lane == 0) {
    const float l0 = a0 + b3[0], l1 = a1 + b3[1], l2 = a2 + b3[2], l3 = a3 + b3[3];
    const float m = fmaxf(fmaxf(l0, l1), fmaxf(l2, l3));
    const float e0 = expf(l0 - m), e1 = expf(l1 - m), e2 = expf(l2 - m), e3 = expf(l3 - m);
    const float ls = logf(e0 + e1 + e2 + e3);
    float4 lp;
    lp.x = l0 - m - ls;
    lp.y = l1 - m - ls;
    lp.z = l2 - m - ls;
    lp.w = l3 - m - ls;
    *(float4*)&logp[row * 4] = lp;
  }
}

__global__ void log_coeffs(const float* __restrict__ coeffs, float* __restrict__ lc) {
  const int v = blockIdx.x * 256 + threadIdx.x;
  if (v < VV) lc[v] = logf(coeffs[v]);
}

// ---------------------------------------------------------------------------
// Gumbel-softmax over count vectors -> mean_z. One block (256 thr) per row.
// ---------------------------------------------------------------------------
__global__ __launch_bounds__(256) void middle(
    const float* __restrict__ logp, const float* __restrict__ rand_grid,
    const float* __restrict__ cv4, const float* __restrict__ lcoef,
    float* __restrict__ mz) {
  __shared__ float s_s[VV];
  __shared__ float sred[4];
  __shared__ float rs[4][5];

  const int b = blockIdx.x;
  const int tid = threadIdx.x;
  const float4 lp = *(const float4*)&logp[b * 4];
  const float* u = rand_grid + (size_t)b * VV;

  float lmax = -INFINITY;
  for (int v = tid; v < VV; v += 256) {
    const float4 c = *(const float4*)&cv4[v * 4];
    float l = lcoef[v] + c.x * lp.x + c.y * lp.y + c.z * lp.z + c.w * lp.w;
    l = fminf(fmaxf(l, LOG_TINY), 0.0f);
    const float g = -logf(-logf(u[v]));
    const float sv = (l + g) * TAU_INV;
    s_s[v] = sv;
    lmax = fmaxf(lmax, sv);
  }
#pragma unroll
  for (int o = 32; o; o >>= 1) lmax = fmaxf(lmax, __shfl_down(lmax, o));
  if ((tid & 63) == 0) sred[tid >> 6] = lmax;
  __syncthreads();
  const float M = fmaxf(fmaxf(sred[0], sred[1]), fmaxf(sred[2], sred[3]));

  float sum = 0.f, w0 = 0.f, w1 = 0.f, w2 = 0.f, w3 = 0.f;
  for (int v = tid; v < VV; v += 256) {
    const float e = expf(s_s[v] - M);
    const float4 c = *(const float4*)&cv4[v * 4];
    sum += e;
    w0 = fmaf(e, c.x, w0);
    w1 = fmaf(e, c.y, w1);
    w2 = fmaf(e, c.z, w2);
    w3 = fmaf(e, c.w, w3);
  }
#pragma unroll
  for (int o = 32; o; o >>= 1) {
    sum += __shfl_down(sum, o);
    w0 += __shfl_down(w0, o);
    w1 += __shfl_down(w1, o);
    w2 += __shfl_down(w2, o);
    w3 += __shfl_down(w3, o);
  }
  if ((tid & 63) == 0) {
    const int w = tid >> 6;
    rs[w][0] = sum; rs[w][1] = w0; rs[w][2] = w1; rs[w][3] = w2; rs[w][4] = w3;
  }
  __syncthreads();
  if (tid == 0) {
    const float S = rs[0][0] + rs[1][0] + rs[2][0] + rs[3][0];
    const float inv = 1.0f / (S * (float)NTRIAL);
    float4 o;
    o.x = (rs[0][1] + rs[1][1] + rs[2][1] + rs[3][1]) * inv;
    o.y = (rs[0][2] + rs[1][2] + rs[2][2] + rs[3][2]) * inv;
    o.z = (rs[0][3] + rs[1][3] + rs[2][3] + rs[3][3]) * inv;
    o.w = (rs[0][4] + rs[1][4] + rs[2][4] + rs[3][4]) * inv;
    *(float4*)&mz[b * 4] = o;
  }
}

// ---------------------------------------------------------------------------
// Decoder layer 1: h3 = relu(mz @ dec_w1 + b1); (B,4)x(4,H) -> hi/lo bf16.
// ---------------------------------------------------------------------------
__global__ __launch_bounds__(256) void dec1(
    const float* __restrict__ mz, const float* __restrict__ w1,
    const float* __restrict__ b1, ushort* __restrict__ h3hl) {
  const int b = blockIdx.x;
  const int j = threadIdx.x << 2;
  const float4 m = *(const float4*)&mz[b * 4];
  float4 acc = *(const float4*)&b1[j];
  const float4 q0 = *(const float4*)&w1[j];
  const float4 q1 = *(const float4*)&w1[HH + j];
  const float4 q2 = *(const float4*)&w1[2 * HH + j];
  const float4 q3 = *(const float4*)&w1[3 * HH + j];
  acc.x = fmaf(m.x, q0.x, fmaf(m.y, q1.x, fmaf(m.z, q2.x, fmaf(m.w, q3.x, acc.x))));
  acc.y = fmaf(m.x, q0.y, fmaf(m.y, q1.y, fmaf(m.z, q2.y, fmaf(m.w, q3.y, acc.y))));
  acc.z = fmaf(m.x, q0.z, fmaf(m.y, q1.z, fmaf(m.z, q2.z, fmaf(m.w, q3.z, acc.z))));
  acc.w = fmaf(m.x, q0.w, fmaf(m.y, q1.w, fmaf(m.z, q2.w, fmaf(m.w, q3.w, acc.w))));
  acc.x = fmaxf(acc.x, 0.f);
  acc.y = fmaxf(acc.y, 0.f);
  acc.z = fmaxf(acc.z, 0.f);
  acc.w = fmaxf(acc.w, 0.f);
  const ushort h0 = f2bf(acc.x), h1 = f2bf(acc.y), h2 = f2bf(acc.z), h3 = f2bf(acc.w);
  const ushort l0 = f2bf(acc.x - bf2f(h0)), l1 = f2bf(acc.y - bf2f(h1));
  const ushort l2 = f2bf(acc.z - bf2f(h2)), l3 = f2bf(acc.w - bf2f(h3));
  uint2 hp, lp;
  hp.x = (uint)h0 | ((uint)h1 << 16); hp.y = (uint)h2 | ((uint)h3 << 16);
  lp.x = (uint)l0 | ((uint)l1 << 16); lp.y = (uint)l2 | ((uint)l3 << 16);
  *(uint2*)&h3hl[(size_t)b * 2048 + j] = hp;
  *(uint2*)&h3hl[(size_t)b * 2048 + 1024 + j] = lp;
}

// ---------------------------------------------------------------------------
// ws layout (36.2 MB): H1hl 16MB | H2hl 16MB | Wt 4MB (reused per GEMM) |
// logp/mz/lcoef small.  Xhl (16 MB) lives in d_out (consumed by GEMM1;
// final GEMM rewrites d_out).
// ---------------------------------------------------------------------------
extern "C" void kernel_launch(void* const* d_in, const int* in_sizes, int n_in,
                              void* d_out, int out_size, void* d_ws, size_t ws_size,
                              hipStream_t stream) {
  const float* x      = (const float*)d_in[0];
  const float* rand_g = (const float*)d_in[1];
  const float* enc_w1 = (const float*)d_in[2];
  const float* enc_b1 = (const float*)d_in[3];
  const float* enc_w2 = (const float*)d_in[4];
  const float* enc_b2 = (const float*)d_in[5];
  const float* enc_w3 = (const float*)d_in[6];
  const float* enc_b3 = (const float*)d_in[7];
  const float* dec_w1 = (const float*)d_in[8];
  const float* dec_b1 = (const float*)d_in[9];
  const float* dec_w2 = (const float*)d_in[10];
  const float* dec_b2 = (const float*)d_in[11];
  const float* dec_w3 = (const float*)d_in[12];
  const float* dec_b3 = (const float*)d_in[13];
  const float* cv4    = (const float*)d_in[14];
  const float* coeffs = (const float*)d_in[15];
  float* out = (float*)d_out;

  ushort* Xhl   = (ushort*)d_out;                      // 4096x2048 = 16 MB exact
  ushort* H1hl  = (ushort*)d_ws;                       // 16 MB
  ushort* H2hl  = H1hl + (size_t)BB * 2048;            // 16 MB
  ushort* Wt    = H2hl + (size_t)BB * 2048;            // 4 MB, reused per GEMM
  float*  logp  = (float*)(Wt + (size_t)1024 * 2048);
  float*  mzp   = logp + BB * 4;
  float*  lcoef = mzp + BB * 4;

  const int mg = 512;                  // (32 m-tiles x 16 n-tiles), XCD-swizzled
  const dim3 wt_grid(32, 32), wt_blk(32, 8);

  log_coeffs<<<(VV + 255) / 256, 256, 0, stream>>>(coeffs, lcoef);
  asplit<<<(BB * DD) / 1024, 256, 0, stream>>>(x, Xhl);

  // encoder
  wsplit_t<<<wt_grid, wt_blk, 0, stream>>>(enc_w1, Wt);
  mfma_gemm<true, true><<<mg, 256, 0, stream>>>(Xhl, Wt, enc_b1, H1hl);
  wsplit_t<<<wt_grid, wt_blk, 0, stream>>>(enc_w2, Wt);
  mfma_gemm<true, true><<<mg, 256, 0, stream>>>(H1hl, Wt, enc_b2, H2hl);
  enc_head<<<BB / 4, 256, 0, stream>>>(H2hl, enc_w3, enc_b3, logp);

  // gumbel-softmax over count vectors
  middle<<<BB, 256, 0, stream>>>(logp, rand_g, cv4, lcoef, mzp);

  // decoder (H1hl reused for h3, H2hl for h4)
  dec1<<<BB, 256, 0, stream>>>(mzp, dec_w1, dec_b1, H1hl);
  wsplit_t<<<wt_grid, wt_blk, 0, stream>>>(dec_w2, Wt);
  mfma_gemm<true, true><<<mg, 256, 0, stream>>>(H1hl, Wt, dec_b2, H2hl);
  wsplit_t<<<wt_grid, wt_blk, 0, stream>>>(dec_w3, Wt);
  mfma_gemm<false, false><<<mg, 256, 0, stream>>>(H2hl, Wt, dec_b3, out);
}